// Round 3
// baseline (404.735 us; speedup 1.0000x reference)
//
#include <hip/hip_runtime.h>
#include <hip/hip_bf16.h>
#include <math.h>

#define TB 2048
#define CC 1024
#define NH 16
#define HD 64
#define NB 4
#define BHX (NB*NH)    // 64
#define BTX (NB*TB)    // 8192

typedef __attribute__((ext_vector_type(8))) short bf16x8;
typedef __attribute__((ext_vector_type(4))) float f32x4;
typedef __attribute__((ext_vector_type(4))) unsigned short us4;

__device__ __forceinline__ unsigned short f2bf(float f) {
  union { float f; unsigned u; } v; v.f = f;
  unsigned r = v.u + 0x7fffu + ((v.u >> 16) & 1u);
  return (unsigned short)(r >> 16);
}
__device__ __forceinline__ float bf2f(unsigned short u) {
  union { unsigned u; float f; } v; v.u = ((unsigned)u) << 16;
  return v.f;
}

__device__ __forceinline__ void gld_lds16(const void* g, void* l) {
  __builtin_amdgcn_global_load_lds(
      (const __attribute__((address_space(1))) unsigned*)g,
      (__attribute__((address_space(3))) unsigned*)l, 16, 0, 0);
}

// RoPE on an 8-element bf16 chunk covering dims [d0, d0+8); fp points at
// freqs_cis flat floats for (t, d0/2): 8 contiguous floats (cos,sin)*4.
__device__ __forceinline__ bf16x8 rope8(bf16x8 raw, const float* fp) {
  f32x4 f0 = *(const f32x4*)fp;
  f32x4 f1 = *(const f32x4*)(fp + 4);
  float cs[8];
  *(f32x4*)cs = f0;
  *(f32x4*)(cs + 4) = f1;
  bf16x8 out;
#pragma unroll
  for (int p = 0; p < 4; p++) {
    float c = cs[2*p], s = cs[2*p+1];
    float x1 = bf2f((unsigned short)raw[2*p]);
    float x2 = bf2f((unsigned short)raw[2*p+1]);
    out[2*p]   = (short)f2bf(x1 * c - x2 * s);
    out[2*p+1] = (short)f2bf(x1 * s + x2 * c);
  }
  return out;
}

__global__ void cvt_f32_bf16(const float* __restrict__ src,
                             unsigned short* __restrict__ dst, int n4) {
  int i = blockIdx.x * blockDim.x + threadIdx.x;
  if (i >= n4) return;
  f32x4 v = ((const f32x4*)src)[i];
  us4 o;
#pragma unroll
  for (int j = 0; j < 4; j++) o[j] = f2bf(v[j]);
  ((us4*)dst)[i] = o;
}

// C[i][n] = sum_k A[i][k]*Bw[n][k] + bias[n].
// MODE 0: f32 output row-major [M][N] (final projection).
// MODE 1: bf16 output scattered to qkv[part][bh][t][d] layout.
template <int MODE>
__global__ __launch_bounds__(256) void gemm_bt(
    const unsigned short* __restrict__ A, const unsigned short* __restrict__ Bw,
    const float* __restrict__ bias, void* __restrict__ Cout,
    int M, int N, int K)
{
  __shared__ __align__(16) unsigned short As[128 * 32];
  __shared__ __align__(16) unsigned short Bs[128 * 32];
  int tid = threadIdx.x;
  int lane = tid & 63, wid = tid >> 6;
  int g = lane >> 4, l4 = lane & 15;
  int wr = wid >> 1, wc = wid & 1;
  int brow = blockIdx.y * 128, bcol = blockIdx.x * 128;

  const unsigned short* ap = A + (size_t)(brow + (tid >> 2)) * K + (tid & 3) * 8;
  const unsigned short* bp_ = Bw + (size_t)(bcol + (tid >> 2)) * K + (tid & 3) * 8;
  const size_t rstep = (size_t)64 * K;
  unsigned short* asl = As + tid * 8;
  unsigned short* bsl = Bs + tid * 8;

  f32x4 acc[4][4] = {};

  for (int k0 = 0; k0 < K; k0 += 32) {
    gld_lds16(ap, asl);
    gld_lds16(ap + rstep, asl + 2048);
    gld_lds16(bp_, bsl);
    gld_lds16(bp_ + rstep, bsl + 2048);
    ap += 32; bp_ += 32;
    __syncthreads();
    bf16x8 af[4], bfr[4];
#pragma unroll
    for (int i = 0; i < 4; i++)
      af[i] = *(const bf16x8*)&As[(wr * 64 + i * 16 + l4) * 32 + g * 8];
#pragma unroll
    for (int i = 0; i < 4; i++)
      bfr[i] = *(const bf16x8*)&Bs[(wc * 64 + i * 16 + l4) * 32 + g * 8];
#pragma unroll
    for (int i = 0; i < 4; i++)
#pragma unroll
      for (int j = 0; j < 4; j++)
        acc[i][j] = __builtin_amdgcn_mfma_f32_16x16x32_bf16(af[i], bfr[j], acc[i][j], 0, 0, 0);
    __syncthreads();
  }

#pragma unroll
  for (int i = 0; i < 4; i++) {
    int grow0 = brow + wr * 64 + i * 16 + 4 * g;
#pragma unroll
    for (int j = 0; j < 4; j++) {
      int gcol = bcol + wc * 64 + j * 16 + l4;
      float bv = bias[gcol];
      if (MODE == 0) {
        float* out = (float*)Cout;
#pragma unroll
        for (int r = 0; r < 4; r++)
          out[(size_t)(grow0 + r) * N + gcol] = acc[i][j][r] + bv;
      } else {
        unsigned short* out = (unsigned short*)Cout;
        int part = gcol >> 10;
        int c = gcol & 1023;
        int h = c >> 6, d = c & 63;
#pragma unroll
        for (int r = 0; r < 4; r++) {
          int grow = grow0 + r;
          int b = grow >> 11, t = grow & 2047;
          size_t dst = (size_t)part * ((size_t)BHX * TB * HD)
                     + ((size_t)(b * NH + h) * TB + t) * HD + d;
          out[dst] = f2bf(acc[i][j][r] + bv);
        }
      }
    }
  }
}

// v [bh][T][64] -> vT [bh][64][T], 64x64 tiles. 256 threads, 2 chunks each way.
__global__ void transpose_v(const unsigned short* __restrict__ v,
                            unsigned short* __restrict__ vT) {
  int bh = blockIdx.y, t0 = blockIdx.x * 64;
  __shared__ __align__(16) unsigned short tile[64][72];
  int tid = threadIdx.x;
#pragma unroll
  for (int s = 0; s < 2; s++) {
    int cid = tid + 256 * s;
    int r = cid >> 3, c8 = (cid & 7) * 8;     // r: t-local 0..63, c8: d 0..56
    bf16x8 val = *(const bf16x8*)(v + ((size_t)bh * TB + t0 + r) * HD + c8);
    *(bf16x8*)&tile[r][c8] = val;
  }
  __syncthreads();
#pragma unroll
  for (int s = 0; s < 2; s++) {
    int cid = tid + 256 * s;
    int rr = cid >> 3, cc = (cid & 7) * 8;    // rr: d 0..63, cc: t-local 0..56
    bf16x8 o;
#pragma unroll
    for (int i = 0; i < 8; i++) o[i] = (short)tile[cc + i][rr];
    *(bf16x8*)(vT + ((size_t)bh * HD + rr) * TB + t0 + cc) = o;
  }
}

// Flash attention fwd, causal. Block = (qt, bh): 64 q-rows, 4 waves x 16 rows.
__global__ __launch_bounds__(256) void flash_fwd(
    const unsigned short* __restrict__ q, const unsigned short* __restrict__ k,
    const unsigned short* __restrict__ vT, const float* __restrict__ fc,
    unsigned short* __restrict__ yb)
{
  int bh = blockIdx.y, qt = blockIdx.x;
  int b = bh >> 4, h = bh & 15;
  int tid = threadIdx.x, wid = tid >> 6, lane = tid & 63;
  int g = lane >> 4, l4 = lane & 15;
  int q0 = qt * 64;
  int qrowA = q0 + wid * 16 + l4;   // A-frag row for Q load
  int qrowD0 = q0 + wid * 16 + 4 * g;  // D-layout row base (+reg j)

  __shared__ __align__(16) unsigned short Ks[64][72];
  __shared__ __align__(16) unsigned short Vs[64][72];
  __shared__ __align__(16) unsigned short Ps[4][16][72];

  // Q fragments with RoPE, held in registers for the whole block.
  bf16x8 qf[2];
  {
    const unsigned short* qp = q + ((size_t)bh * TB + qrowA) * HD;
    const float* fp = fc + (size_t)qrowA * 64;
#pragma unroll
    for (int kk = 0; kk < 2; kk++) {
      int d0 = kk * 32 + g * 8;
      bf16x8 raw = *(const bf16x8*)(qp + d0);
      qf[kk] = rope8(raw, fp + d0);
    }
  }

  float m_run[4], l_run[4];
  f32x4 acc_o[4] = {};
#pragma unroll
  for (int j = 0; j < 4; j++) { m_run[j] = -1e30f; l_run[j] = 0.f; }

  for (int kt = 0; kt <= qt; kt++) {
    int k0 = kt * 64;
    __syncthreads();
    // Stage K (with RoPE) and V^T tiles: 2x 16B chunks per thread each.
#pragma unroll
    for (int s = 0; s < 2; s++) {
      int cid = tid + 256 * s;
      int rr = cid >> 3, cc = (cid & 7) * 8;
      bf16x8 kraw = *(const bf16x8*)(k + ((size_t)bh * TB + k0 + rr) * HD + cc);
      *(bf16x8*)&Ks[rr][cc] = rope8(kraw, fc + (size_t)(k0 + rr) * 64 + cc);
      *(bf16x8*)&Vs[rr][cc] = *(const bf16x8*)(vT + ((size_t)bh * HD + rr) * TB + k0 + cc);
    }
    __syncthreads();

    // S = Q K^T (16 q-rows x 64 kv), scaled + causal-masked.
    float sv[4][4];
#pragma unroll
    for (int cb = 0; cb < 4; cb++) {
      bf16x8 kb0 = *(const bf16x8*)&Ks[cb * 16 + l4][g * 8];
      bf16x8 kb1 = *(const bf16x8*)&Ks[cb * 16 + l4][32 + g * 8];
      f32x4 z = {0.f, 0.f, 0.f, 0.f};
      z = __builtin_amdgcn_mfma_f32_16x16x32_bf16(qf[0], kb0, z, 0, 0, 0);
      z = __builtin_amdgcn_mfma_f32_16x16x32_bf16(qf[1], kb1, z, 0, 0, 0);
#pragma unroll
      for (int j = 0; j < 4; j++) {
        float s = z[j] * 0.125f;
        if (kt == qt) {
          int kcol = k0 + cb * 16 + l4;
          if (kcol > qrowD0 + j) s = -1e30f;
        }
        sv[cb][j] = s;
      }
    }

    // Online softmax (rows live in 16-lane groups; reduce via shfl_xor).
    float mt[4];
#pragma unroll
    for (int j = 0; j < 4; j++)
      mt[j] = fmaxf(fmaxf(sv[0][j], sv[1][j]), fmaxf(sv[2][j], sv[3][j]));
#pragma unroll
    for (int off = 1; off < 16; off <<= 1)
#pragma unroll
      for (int j = 0; j < 4; j++)
        mt[j] = fmaxf(mt[j], __shfl_xor(mt[j], off, 64));
    float alpha[4];
#pragma unroll
    for (int j = 0; j < 4; j++) {
      float mn = fmaxf(m_run[j], mt[j]);
      alpha[j] = __expf(m_run[j] - mn);
      m_run[j] = mn;
    }
    float ps[4] = {0.f, 0.f, 0.f, 0.f};
#pragma unroll
    for (int cb = 0; cb < 4; cb++)
#pragma unroll
      for (int j = 0; j < 4; j++) {
        float p = __expf(sv[cb][j] - m_run[j]);
        sv[cb][j] = p;
        ps[j] += p;
      }
#pragma unroll
    for (int off = 1; off < 16; off <<= 1)
#pragma unroll
      for (int j = 0; j < 4; j++)
        ps[j] += __shfl_xor(ps[j], off, 64);
#pragma unroll
    for (int j = 0; j < 4; j++)
      l_run[j] = l_run[j] * alpha[j] + ps[j];
#pragma unroll
    for (int db = 0; db < 4; db++)
#pragma unroll
      for (int j = 0; j < 4; j++)
        acc_o[db][j] *= alpha[j];

    // P -> LDS (per-wave region) -> A-fragment for PV.
#pragma unroll
    for (int cb = 0; cb < 4; cb++)
#pragma unroll
      for (int j = 0; j < 4; j++)
        Ps[wid][4 * g + j][cb * 16 + l4] = f2bf(sv[cb][j]);
    asm volatile("s_waitcnt lgkmcnt(0)" ::: "memory");
    bf16x8 pa0 = *(const bf16x8*)&Ps[wid][l4][g * 8];
    bf16x8 pa1 = *(const bf16x8*)&Ps[wid][l4][32 + g * 8];
#pragma unroll
    for (int db = 0; db < 4; db++) {
      bf16x8 vb0 = *(const bf16x8*)&Vs[db * 16 + l4][g * 8];
      bf16x8 vb1 = *(const bf16x8*)&Vs[db * 16 + l4][32 + g * 8];
      acc_o[db] = __builtin_amdgcn_mfma_f32_16x16x32_bf16(pa0, vb0, acc_o[db], 0, 0, 0);
      acc_o[db] = __builtin_amdgcn_mfma_f32_16x16x32_bf16(pa1, vb1, acc_o[db], 0, 0, 0);
    }
  }

  // Epilogue: normalize and write y[b][t][h*64+d] as bf16.
#pragma unroll
  for (int j = 0; j < 4; j++) l_run[j] = 1.0f / l_run[j];
  unsigned short* yp = yb + ((size_t)b * TB) * CC + (size_t)h * HD;
#pragma unroll
  for (int db = 0; db < 4; db++) {
    int d = db * 16 + l4;
#pragma unroll
    for (int j = 0; j < 4; j++) {
      int qr = qrowD0 + j;
      yp[(size_t)qr * CC + d] = f2bf(acc_o[db][j] * l_run[j]);
    }
  }
}

extern "C" void kernel_launch(void* const* d_in, const int* in_sizes, int n_in,
                              void* d_out, int out_size, void* d_ws, size_t ws_size,
                              hipStream_t stream) {
  (void)in_sizes; (void)n_in; (void)out_size; (void)ws_size;
  const float* x  = (const float*)d_in[0];
  const float* fc = (const float*)d_in[1];
  // d_in[2]=attn_mask (tril), d_in[3]=padding_mask (all ones): applied analytically.
  const float* Wq = (const float*)d_in[4];
  const float* bq = (const float*)d_in[5];
  const float* Wk = (const float*)d_in[6];
  const float* bk = (const float*)d_in[7];
  const float* Wv = (const float*)d_in[8];
  const float* bv = (const float*)d_in[9];
  const float* Wp = (const float*)d_in[10];
  const float* bp = (const float*)d_in[11];

  char* ws = (char*)d_ws;
  unsigned short* xb   = (unsigned short*)(ws + 0);          // 8192x1024 bf16 (later reused as yb)
  unsigned short* wqkv = (unsigned short*)(ws + 16777216);   // 3072x1024 bf16
  unsigned short* wp   = (unsigned short*)(ws + 23068672);   // 1024x1024 bf16
  float*          bqkv = (float*)(ws + 25165824);            // 3072 f32
  unsigned short* qkv  = (unsigned short*)(ws + 25182208);   // 3 x [64][2048][64] bf16
  unsigned short* vT   = qkv + 3 * (size_t)8388608;          // [64][64][2048] bf16
  unsigned short* yb   = xb;

  cvt_f32_bf16<<<(2097152 + 255) / 256, 256, 0, stream>>>(x, xb, 2097152);
  cvt_f32_bf16<<<(262144 + 255) / 256, 256, 0, stream>>>(Wq, wqkv, 262144);
  cvt_f32_bf16<<<(262144 + 255) / 256, 256, 0, stream>>>(Wk, wqkv + 1048576, 262144);
  cvt_f32_bf16<<<(262144 + 255) / 256, 256, 0, stream>>>(Wv, wqkv + 2097152, 262144);
  cvt_f32_bf16<<<(262144 + 255) / 256, 256, 0, stream>>>(Wp, wp, 262144);
  hipMemcpyAsync(bqkv,        bq, 4096, hipMemcpyDeviceToDevice, stream);
  hipMemcpyAsync(bqkv + 1024, bk, 4096, hipMemcpyDeviceToDevice, stream);
  hipMemcpyAsync(bqkv + 2048, bv, 4096, hipMemcpyDeviceToDevice, stream);

  gemm_bt<1><<<dim3(24, 64), 256, 0, stream>>>(xb, wqkv, bqkv, qkv, BTX, 3072, 1024);
  transpose_v<<<dim3(32, 64), 256, 0, stream>>>(qkv + 2 * (size_t)8388608, vT);
  flash_fwd<<<dim3(32, 64), 256, 0, stream>>>(qkv, qkv + (size_t)8388608, vT, fc, yb);
  gemm_bt<0><<<dim3(8, 64), 256, 0, stream>>>(yb, wp, bp, (float*)d_out, BTX, 1024, 1024);
}

// Round 4
// 320.903 us; speedup vs baseline: 1.2612x; 1.2612x over previous
//
#include <hip/hip_runtime.h>
#include <hip/hip_bf16.h>
#include <math.h>

#define TB 2048
#define CC 1024
#define NH 16
#define HD 64
#define NB 4
#define BHX (NB*NH)    // 64
#define BTX (NB*TB)    // 8192

typedef __attribute__((ext_vector_type(8))) short bf16x8;
typedef __attribute__((ext_vector_type(4))) float f32x4;
typedef __attribute__((ext_vector_type(4))) unsigned short us4;

__device__ __forceinline__ unsigned short f2bf(float f) {
  union { float f; unsigned u; } v; v.f = f;
  unsigned r = v.u + 0x7fffu + ((v.u >> 16) & 1u);
  return (unsigned short)(r >> 16);
}
__device__ __forceinline__ float bf2f(unsigned short u) {
  union { unsigned u; float f; } v; v.u = ((unsigned)u) << 16;
  return v.f;
}

__device__ __forceinline__ void gld_lds16(const void* g, void* l) {
  __builtin_amdgcn_global_load_lds(
      (const __attribute__((address_space(1))) unsigned*)g,
      (__attribute__((address_space(3))) unsigned*)l, 16, 0, 0);
}

__global__ void cvt_f32_bf16(const float* __restrict__ src,
                             unsigned short* __restrict__ dst, int n4) {
  int i = blockIdx.x * blockDim.x + threadIdx.x;
  if (i >= n4) return;
  f32x4 v = ((const f32x4*)src)[i];
  us4 o;
#pragma unroll
  for (int j = 0; j < 4; j++) o[j] = f2bf(v[j]);
  ((us4*)dst)[i] = o;
}

// C[i][n] = sum_k A[i][k]*Bw[n][k] + bias[n].
// MODE 0: f32 output row-major [M][N] (final projection).
// MODE 1: bf16 output scattered to qkv[part][bh][t][d] layout, with RoPE
//         applied to parts 0,1 (q,k) via shfl partner exchange.
template <int MODE>
__global__ __launch_bounds__(256) void gemm_bt(
    const unsigned short* __restrict__ A, const unsigned short* __restrict__ Bw,
    const float* __restrict__ bias, const float* __restrict__ fcg,
    void* __restrict__ Cout, int M, int N, int K)
{
  __shared__ __align__(16) unsigned short As[128 * 32];
  __shared__ __align__(16) unsigned short Bs[128 * 32];
  int tid = threadIdx.x;
  int lane = tid & 63, wid = tid >> 6;
  int g = lane >> 4, l4 = lane & 15;
  int wr = wid >> 1, wc = wid & 1;
  int brow = blockIdx.y * 128, bcol = blockIdx.x * 128;

  const unsigned short* ap = A + (size_t)(brow + (tid >> 2)) * K + (tid & 3) * 8;
  const unsigned short* bp_ = Bw + (size_t)(bcol + (tid >> 2)) * K + (tid & 3) * 8;
  const size_t rstep = (size_t)64 * K;
  unsigned short* asl = As + tid * 8;
  unsigned short* bsl = Bs + tid * 8;

  f32x4 acc[4][4] = {};

  for (int k0 = 0; k0 < K; k0 += 32) {
    gld_lds16(ap, asl);
    gld_lds16(ap + rstep, asl + 2048);
    gld_lds16(bp_, bsl);
    gld_lds16(bp_ + rstep, bsl + 2048);
    ap += 32; bp_ += 32;
    __syncthreads();
    bf16x8 af[4], bfr[4];
#pragma unroll
    for (int i = 0; i < 4; i++)
      af[i] = *(const bf16x8*)&As[(wr * 64 + i * 16 + l4) * 32 + g * 8];
#pragma unroll
    for (int i = 0; i < 4; i++)
      bfr[i] = *(const bf16x8*)&Bs[(wc * 64 + i * 16 + l4) * 32 + g * 8];
#pragma unroll
    for (int i = 0; i < 4; i++)
#pragma unroll
      for (int j = 0; j < 4; j++)
        acc[i][j] = __builtin_amdgcn_mfma_f32_16x16x32_bf16(af[i], bfr[j], acc[i][j], 0, 0, 0);
    __syncthreads();
  }

#pragma unroll
  for (int i = 0; i < 4; i++) {
    int grow0 = brow + wr * 64 + i * 16 + 4 * g;
#pragma unroll
    for (int j = 0; j < 4; j++) {
      int gcol = bcol + wc * 64 + j * 16 + l4;
      float bv = bias[gcol];
      if (MODE == 0) {
        float* out = (float*)Cout;
#pragma unroll
        for (int r = 0; r < 4; r++)
          out[(size_t)(grow0 + r) * N + gcol] = acc[i][j][r] + bv;
      } else {
        unsigned short* out = (unsigned short*)Cout;
        int part = gcol >> 10;
        int c = gcol & 1023;
        int h = c >> 6, d = c & 63;
        int dbase = d & ~1;
        float sgn = (d & 1) ? 1.f : -1.f;
        bool isqk = (part < 2);   // uniform across the l4/l4^1 pair
#pragma unroll
        for (int r = 0; r < 4; r++) {
          int grow = grow0 + r;
          int b = grow >> 11, t = grow & 2047;
          float v = acc[i][j][r] + bv;
          float w = __shfl_xor(v, 1, 64);  // partner dim's value
          float o = v;
          if (isqk) {
            float cth = fcg[(size_t)t * 64 + dbase];
            float sth = fcg[(size_t)t * 64 + dbase + 1];
            o = v * cth + sgn * w * sth;
          }
          size_t dst = (size_t)part * ((size_t)BHX * TB * HD)
                     + ((size_t)(b * NH + h) * TB + t) * HD + d;
          out[dst] = f2bf(o);
        }
      }
    }
  }
}

// v [bh][T][64] -> vT [bh][64][T], 64x64 tiles. 256 threads, 2 chunks each way.
__global__ void transpose_v(const unsigned short* __restrict__ v,
                            unsigned short* __restrict__ vT) {
  int bh = blockIdx.y, t0 = blockIdx.x * 64;
  __shared__ __align__(16) unsigned short tile[64][72];
  int tid = threadIdx.x;
#pragma unroll
  for (int s = 0; s < 2; s++) {
    int cid = tid + 256 * s;
    int r = cid >> 3, c8 = (cid & 7) * 8;
    bf16x8 val = *(const bf16x8*)(v + ((size_t)bh * TB + t0 + r) * HD + c8);
    *(bf16x8*)&tile[r][c8] = val;
  }
  __syncthreads();
#pragma unroll
  for (int s = 0; s < 2; s++) {
    int cid = tid + 256 * s;
    int rr = cid >> 3, cc = (cid & 7) * 8;
    bf16x8 o;
#pragma unroll
    for (int i = 0; i < 8; i++) o[i] = (short)tile[cc + i][rr];
    *(bf16x8*)(vT + ((size_t)bh * HD + rr) * TB + t0 + cc) = o;
  }
}

// Flash attention fwd, causal. Block = (bh, qt): 128 q-rows, 4 waves x 2x16 rows.
// K/V pre-roped (K) / transposed (V^T); staged via global_load_lds with
// XOR-swizzled source (chunk ^= row&7) so ds_read_b128 is conflict-free.
__global__ __launch_bounds__(256) void flash_fwd(
    const unsigned short* __restrict__ q, const unsigned short* __restrict__ k,
    const unsigned short* __restrict__ vT, unsigned short* __restrict__ yb)
{
  int bh = blockIdx.x, qt = blockIdx.y;
  int b = bh >> 4, h = bh & 15;
  int tid = threadIdx.x, wid = tid >> 6, lane = tid & 63;
  int g = lane >> 4, l4 = lane & 15;
  int q0 = qt * 128;

  __shared__ __align__(16) unsigned short Ks[64 * 64];  // linear, swz content
  __shared__ __align__(16) unsigned short Vs[64 * 64];  // linear, swz content
  __shared__ __align__(16) unsigned short Ps[4][16][72];

  // Q fragments (already roped by GEMM epilogue).
  bf16x8 qf[2][2];
#pragma unroll
  for (int rb = 0; rb < 2; rb++) {
    const unsigned short* qp = q + ((size_t)(bh * TB + q0 + wid * 32 + rb * 16 + l4)) * HD;
    qf[rb][0] = *(const bf16x8*)(qp + g * 8);
    qf[rb][1] = *(const bf16x8*)(qp + 32 + g * 8);
  }

  float m_run[2][4], l_run[2][4];
  f32x4 acc_o[2][4] = {};
#pragma unroll
  for (int rb = 0; rb < 2; rb++)
#pragma unroll
    for (int j = 0; j < 4; j++) { m_run[rb][j] = -1e30f; l_run[rb][j] = 0.f; }

  const int bhK = bh * TB;
  const int bhV = bh * HD;
  const int off0 = (wid << 10) + ((lane) << 4);
  const int ktn = 2 * qt + 2;

  for (int kt = 0; kt < ktn; kt++) {
    int k0 = kt * 64;
    __syncthreads();
    // Stage K and V^T tiles (8KB each) via gld_lds, source pre-swizzled.
#pragma unroll
    for (int s = 0; s < 2; s++) {
      int off = off0 + (s << 12);       // byte offset in 8KB tile
      int row = off >> 7;               // 0..63
      int cc  = (off >> 4) & 7;         // 16B chunk in row
      int sc  = cc ^ (row & 7);         // inverse-swizzled source chunk
      gld_lds16(k  + ((size_t)(bhK + k0 + row) << 6) + (sc << 3), Ks + (off >> 1));
      gld_lds16(vT + ((size_t)(bhV + row) << 11) + k0 + (sc << 3), Vs + (off >> 1));
    }
    __syncthreads();

#pragma unroll
    for (int rb = 0; rb < 2; rb++) {
      int rbase = q0 + wid * 32 + rb * 16;
      if (k0 > rbase + 15) continue;   // fully masked row-block (wave-uniform)
      int qr0 = rbase + 4 * g;         // D-layout row base (+j)

      // S = Q K^T (16 q-rows x 64 kv), scaled + causal-masked.
      float sv[4][4];
      bool diag = (k0 + 63 > qr0);
#pragma unroll
      for (int cb = 0; cb < 4; cb++) {
        int r = cb * 16 + l4;
        int sw = (r & 7) * 8;
        bf16x8 kb0 = *(const bf16x8*)&Ks[r * 64 + ((g * 8) ^ sw)];
        bf16x8 kb1 = *(const bf16x8*)&Ks[r * 64 + (((g + 4) * 8) ^ sw)];
        f32x4 z = {0.f, 0.f, 0.f, 0.f};
        z = __builtin_amdgcn_mfma_f32_16x16x32_bf16(qf[rb][0], kb0, z, 0, 0, 0);
        z = __builtin_amdgcn_mfma_f32_16x16x32_bf16(qf[rb][1], kb1, z, 0, 0, 0);
#pragma unroll
        for (int j = 0; j < 4; j++) {
          float s = z[j] * 0.125f;
          if (diag) {
            int kcol = k0 + cb * 16 + l4;
            if (kcol > qr0 + j) s = -1e30f;
          }
          sv[cb][j] = s;
        }
      }

      // Online softmax (rows in 16-lane groups; reduce via shfl_xor).
      float mt[4];
#pragma unroll
      for (int j = 0; j < 4; j++)
        mt[j] = fmaxf(fmaxf(sv[0][j], sv[1][j]), fmaxf(sv[2][j], sv[3][j]));
#pragma unroll
      for (int off = 1; off < 16; off <<= 1)
#pragma unroll
        for (int j = 0; j < 4; j++)
          mt[j] = fmaxf(mt[j], __shfl_xor(mt[j], off, 64));
      float alpha[4];
#pragma unroll
      for (int j = 0; j < 4; j++) {
        float mn = fmaxf(m_run[rb][j], mt[j]);
        alpha[j] = __expf(m_run[rb][j] - mn);
        m_run[rb][j] = mn;
      }
      float ps[4] = {0.f, 0.f, 0.f, 0.f};
#pragma unroll
      for (int cb = 0; cb < 4; cb++)
#pragma unroll
        for (int j = 0; j < 4; j++) {
          float p = __expf(sv[cb][j] - m_run[rb][j]);
          sv[cb][j] = p;
          ps[j] += p;
        }
#pragma unroll
      for (int off = 1; off < 16; off <<= 1)
#pragma unroll
        for (int j = 0; j < 4; j++)
          ps[j] += __shfl_xor(ps[j], off, 64);
#pragma unroll
      for (int j = 0; j < 4; j++)
        l_run[rb][j] = l_run[rb][j] * alpha[j] + ps[j];
#pragma unroll
      for (int db = 0; db < 4; db++)
#pragma unroll
        for (int j = 0; j < 4; j++)
          acc_o[rb][db][j] *= alpha[j];

      // P -> LDS (per-wave region, reused across rb) -> A-fragment for PV.
#pragma unroll
      for (int cb = 0; cb < 4; cb++)
#pragma unroll
        for (int j = 0; j < 4; j++)
          Ps[wid][4 * g + j][cb * 16 + l4] = f2bf(sv[cb][j]);
      asm volatile("s_waitcnt lgkmcnt(0)" ::: "memory");
      __builtin_amdgcn_sched_barrier(0);
      bf16x8 pa0 = *(const bf16x8*)&Ps[wid][l4][g * 8];
      bf16x8 pa1 = *(const bf16x8*)&Ps[wid][l4][32 + g * 8];
#pragma unroll
      for (int db = 0; db < 4; db++) {
        int r = db * 16 + l4;
        int sw = (r & 7) * 8;
        bf16x8 vb0 = *(const bf16x8*)&Vs[r * 64 + ((g * 8) ^ sw)];
        bf16x8 vb1 = *(const bf16x8*)&Vs[r * 64 + (((g + 4) * 8) ^ sw)];
        acc_o[rb][db] = __builtin_amdgcn_mfma_f32_16x16x32_bf16(pa0, vb0, acc_o[rb][db], 0, 0, 0);
        acc_o[rb][db] = __builtin_amdgcn_mfma_f32_16x16x32_bf16(pa1, vb1, acc_o[rb][db], 0, 0, 0);
      }
    }
  }

  // Epilogue: normalize and write y[b][t][h*64+d] as bf16.
  unsigned short* yp = yb + ((size_t)b * TB) * CC + (size_t)h * HD;
#pragma unroll
  for (int rb = 0; rb < 2; rb++) {
    int qr0 = q0 + wid * 32 + rb * 16 + 4 * g;
    float inv[4];
#pragma unroll
    for (int j = 0; j < 4; j++) inv[j] = 1.0f / l_run[rb][j];
#pragma unroll
    for (int db = 0; db < 4; db++) {
      int d = db * 16 + l4;
#pragma unroll
      for (int j = 0; j < 4; j++)
        yp[(size_t)(qr0 + j) * CC + d] = f2bf(acc_o[rb][db][j] * inv[j]);
    }
  }
}

extern "C" void kernel_launch(void* const* d_in, const int* in_sizes, int n_in,
                              void* d_out, int out_size, void* d_ws, size_t ws_size,
                              hipStream_t stream) {
  (void)in_sizes; (void)n_in; (void)out_size; (void)ws_size;
  const float* x  = (const float*)d_in[0];
  const float* fc = (const float*)d_in[1];
  // d_in[2]=attn_mask (tril), d_in[3]=padding_mask (all ones): applied analytically.
  const float* Wq = (const float*)d_in[4];
  const float* bq = (const float*)d_in[5];
  const float* Wk = (const float*)d_in[6];
  const float* bk = (const float*)d_in[7];
  const float* Wv = (const float*)d_in[8];
  const float* bv = (const float*)d_in[9];
  const float* Wp = (const float*)d_in[10];
  const float* bp = (const float*)d_in[11];

  char* ws = (char*)d_ws;
  unsigned short* xb   = (unsigned short*)(ws + 0);          // 8192x1024 bf16 (later reused as yb)
  unsigned short* wqkv = (unsigned short*)(ws + 16777216);   // 3072x1024 bf16
  unsigned short* wp   = (unsigned short*)(ws + 23068672);   // 1024x1024 bf16
  float*          bqkv = (float*)(ws + 25165824);            // 3072 f32
  unsigned short* qkv  = (unsigned short*)(ws + 25182208);   // 3 x [64][2048][64] bf16
  unsigned short* vT   = qkv + 3 * (size_t)8388608;          // [64][64][2048] bf16
  unsigned short* yb   = xb;

  cvt_f32_bf16<<<(2097152 + 255) / 256, 256, 0, stream>>>(x, xb, 2097152);
  cvt_f32_bf16<<<(262144 + 255) / 256, 256, 0, stream>>>(Wq, wqkv, 262144);
  cvt_f32_bf16<<<(262144 + 255) / 256, 256, 0, stream>>>(Wk, wqkv + 1048576, 262144);
  cvt_f32_bf16<<<(262144 + 255) / 256, 256, 0, stream>>>(Wv, wqkv + 2097152, 262144);
  cvt_f32_bf16<<<(262144 + 255) / 256, 256, 0, stream>>>(Wp, wp, 262144);
  hipMemcpyAsync(bqkv,        bq, 4096, hipMemcpyDeviceToDevice, stream);
  hipMemcpyAsync(bqkv + 1024, bk, 4096, hipMemcpyDeviceToDevice, stream);
  hipMemcpyAsync(bqkv + 2048, bv, 4096, hipMemcpyDeviceToDevice, stream);

  gemm_bt<1><<<dim3(24, 64), 256, 0, stream>>>(xb, wqkv, bqkv, fc, qkv, BTX, 3072, 1024);
  transpose_v<<<dim3(32, 64), 256, 0, stream>>>(qkv + 2 * (size_t)8388608, vT);
  flash_fwd<<<dim3(64, 16), 256, 0, stream>>>(qkv, qkv + (size_t)8388608, vT, yb);
  gemm_bt<0><<<dim3(8, 64), 256, 0, stream>>>(yb, wp, bp, nullptr, (float*)d_out, BTX, 1024, 1024);
}

// Round 6
// 305.763 us; speedup vs baseline: 1.3237x; 1.0495x over previous
//
#include <hip/hip_runtime.h>
#include <hip/hip_bf16.h>

#define TB 2048
#define CC 1024
#define NH 16
#define HD 64
#define NB 4
#define BHX (NB*NH)    // 64
#define BTX (NB*TB)    // 8192
#define NITEMS 2048

typedef __attribute__((ext_vector_type(8))) short bf16x8;
typedef __attribute__((ext_vector_type(4))) float f32x4;
typedef __attribute__((ext_vector_type(4))) unsigned short us4;

__device__ __forceinline__ unsigned short f2bf(float f) {
  union { float f; unsigned u; } v; v.f = f;
  unsigned r = v.u + 0x7fffu + ((v.u >> 16) & 1u);
  return (unsigned short)(r >> 16);
}
__device__ __forceinline__ float bf2f(unsigned short u) {
  union { unsigned u; float f; } v; v.u = ((unsigned)u) << 16;
  return v.f;
}
__device__ __forceinline__ float fexp2(float x) {
  return __builtin_amdgcn_exp2f(x);   // v_exp_f32 (2^x)
}

__device__ __forceinline__ void gld_lds16(const void* g, void* l) {
  __builtin_amdgcn_global_load_lds(
      (const __attribute__((address_space(1))) unsigned*)g,
      (__attribute__((address_space(3))) unsigned*)l, 16, 0, 0);
}

__global__ void cvt_f32_bf16(const float* __restrict__ src,
                             unsigned short* __restrict__ dst, int n4) {
  int i = blockIdx.x * blockDim.x + threadIdx.x;
  if (i >= n4) return;
  f32x4 v = ((const f32x4*)src)[i];
  us4 o;
#pragma unroll
  for (int j = 0; j < 4; j++) o[j] = f2bf(v[j]);
  ((us4*)dst)[i] = o;
}

// C[i][n] = sum_k A[i][k]*Bw[n][k] + bias[n].
// MODE 0: f32 output row-major [M][N] (final projection).
// MODE 1: bf16 output scattered to qkv[part][bh][t][d] layout, with RoPE
//         applied to parts 0,1 (q,k) via shfl partner exchange.
template <int MODE>
__global__ __launch_bounds__(256) void gemm_bt(
    const unsigned short* __restrict__ A, const unsigned short* __restrict__ Bw,
    const float* __restrict__ bias, const float* __restrict__ fcg,
    void* __restrict__ Cout, int M, int N, int K)
{
  __shared__ __align__(16) unsigned short As[128 * 32];
  __shared__ __align__(16) unsigned short Bs[128 * 32];
  int tid = threadIdx.x;
  int lane = tid & 63, wid = tid >> 6;
  int g = lane >> 4, l4 = lane & 15;
  int wr = wid >> 1, wc = wid & 1;
  int brow = blockIdx.y * 128, bcol = blockIdx.x * 128;

  const unsigned short* ap = A + (size_t)(brow + (tid >> 2)) * K + (tid & 3) * 8;
  const unsigned short* bp_ = Bw + (size_t)(bcol + (tid >> 2)) * K + (tid & 3) * 8;
  const size_t rstep = (size_t)64 * K;
  unsigned short* asl = As + tid * 8;
  unsigned short* bsl = Bs + tid * 8;

  f32x4 acc[4][4] = {};

  for (int k0 = 0; k0 < K; k0 += 32) {
    gld_lds16(ap, asl);
    gld_lds16(ap + rstep, asl + 2048);
    gld_lds16(bp_, bsl);
    gld_lds16(bp_ + rstep, bsl + 2048);
    ap += 32; bp_ += 32;
    __syncthreads();
    bf16x8 af[4], bfr[4];
#pragma unroll
    for (int i = 0; i < 4; i++)
      af[i] = *(const bf16x8*)&As[(wr * 64 + i * 16 + l4) * 32 + g * 8];
#pragma unroll
    for (int i = 0; i < 4; i++)
      bfr[i] = *(const bf16x8*)&Bs[(wc * 64 + i * 16 + l4) * 32 + g * 8];
#pragma unroll
    for (int i = 0; i < 4; i++)
#pragma unroll
      for (int j = 0; j < 4; j++)
        acc[i][j] = __builtin_amdgcn_mfma_f32_16x16x32_bf16(af[i], bfr[j], acc[i][j], 0, 0, 0);
    __syncthreads();
  }

#pragma unroll
  for (int i = 0; i < 4; i++) {
    int grow0 = brow + wr * 64 + i * 16 + 4 * g;
#pragma unroll
    for (int j = 0; j < 4; j++) {
      int gcol = bcol + wc * 64 + j * 16 + l4;
      float bv = bias[gcol];
      if (MODE == 0) {
        float* out = (float*)Cout;
#pragma unroll
        for (int r = 0; r < 4; r++)
          out[(size_t)(grow0 + r) * N + gcol] = acc[i][j][r] + bv;
      } else {
        unsigned short* out = (unsigned short*)Cout;
        int part = gcol >> 10;
        int c = gcol & 1023;
        int h = c >> 6, d = c & 63;
        int dbase = d & ~1;
        float sgn = (d & 1) ? 1.f : -1.f;
        bool isqk = (part < 2);   // uniform across the l4/l4^1 pair
#pragma unroll
        for (int r = 0; r < 4; r++) {
          int grow = grow0 + r;
          int b = grow >> 11, t = grow & 2047;
          float v = acc[i][j][r] + bv;
          float w = __shfl_xor(v, 1, 64);  // partner dim's value
          float o = v;
          if (isqk) {
            float cth = fcg[(size_t)t * 64 + dbase];
            float sth = fcg[(size_t)t * 64 + dbase + 1];
            o = v * cth + sgn * w * sth;
          }
          size_t dst = (size_t)part * ((size_t)BHX * TB * HD)
                     + ((size_t)(b * NH + h) * TB + t) * HD + d;
          out[dst] = f2bf(o);
        }
      }
    }
  }
}

// v [bh][T][64] -> vT [bh][64][T], 64x64 tiles. 256 threads, 2 chunks each way.
__global__ void transpose_v(const unsigned short* __restrict__ v,
                            unsigned short* __restrict__ vT) {
  int bh = blockIdx.y, t0 = blockIdx.x * 64;
  __shared__ __align__(16) unsigned short tile[64][72];
  int tid = threadIdx.x;
#pragma unroll
  for (int s = 0; s < 2; s++) {
    int cid = tid + 256 * s;
    int r = cid >> 3, c8 = (cid & 7) * 8;
    bf16x8 val = *(const bf16x8*)(v + ((size_t)bh * TB + t0 + r) * HD + c8);
    *(bf16x8*)&tile[r][c8] = val;
  }
  __syncthreads();
#pragma unroll
  for (int s = 0; s < 2; s++) {
    int cid = tid + 256 * s;
    int rr = cid >> 3, cc = (cid & 7) * 8;
    bf16x8 o;
#pragma unroll
    for (int i = 0; i < 8; i++) o[i] = (short)tile[cc + i][rr];
    *(bf16x8*)(vT + ((size_t)bh * HD + rr) * TB + t0 + cc) = o;
  }
}

// Flash attention fwd, causal. Work-stealing over 2048 items (bh, q64):
// 64 q-rows per item, 4 waves x 16 rows, KV tiles of 64. Heavy items first.
// K pre-roped, V^T pre-transposed; K/V staged via global_load_lds with
// XOR-swizzled source so ds_read_b128 is spread across banks.
__global__ __launch_bounds__(256) void flash_fwd(
    const unsigned short* __restrict__ q, const unsigned short* __restrict__ k,
    const unsigned short* __restrict__ vT, unsigned short* __restrict__ yb,
    int* __restrict__ ctr)
{
  __shared__ __align__(16) unsigned short Ks[64 * 64];  // linear, swz content
  __shared__ __align__(16) unsigned short Vs[64 * 64];  // linear, swz content
  __shared__ __align__(16) unsigned short Ps[4][16][72];
  __shared__ int s_item;

  const int tid = threadIdx.x, wid = tid >> 6, lane = tid & 63;
  const int g = lane >> 4, l4 = lane & 15;

  // fixed staging geometry: 2 passes x 16B per thread per tile
  const int off0 = tid << 4;                       // bytes in 4KB pass 0
  const int row0 = off0 >> 7, sc0 = ((off0 >> 4) & 7) ^ (row0 & 7);
  const int off1 = off0 + 4096;
  const int row1 = off1 >> 7, sc1 = ((off1 >> 4) & 7) ^ (row1 & 7);
  unsigned short* kd0 = Ks + (off0 >> 1);
  unsigned short* kd1 = Ks + (off1 >> 1);
  unsigned short* vd0 = Vs + (off0 >> 1);
  unsigned short* vd1 = Vs + (off1 >> 1);

  const float SCL2 = 0.18033688011112042f;  // 1/8 * log2(e)

  for (;;) {
    __syncthreads();
    if (tid == 0) s_item = atomicAdd(ctr, 1);
    __syncthreads();
    const int w = s_item;
    if (w >= NITEMS) break;
    const int q64 = 31 - (w >> 6), bh = w & 63;
    const int rbase = q64 * 64 + wid * 16;   // wave's absolute q-row base

    const unsigned short* kp0 = k  + (((size_t)bh * TB + row0) << 6) + (sc0 << 3);
    const unsigned short* kp1 = k  + (((size_t)bh * TB + row1) << 6) + (sc1 << 3);
    const unsigned short* vp0 = vT + (((size_t)bh * HD + row0) << 11) + (sc0 << 3);
    const unsigned short* vp1 = vT + (((size_t)bh * HD + row1) << 11) + (sc1 << 3);

    // Q fragments (pre-roped by GEMM epilogue)
    bf16x8 qf0, qf1;
    {
      const unsigned short* qp = q + (((size_t)bh * TB + rbase + l4) << 6);
      qf0 = *(const bf16x8*)(qp + g * 8);
      qf1 = *(const bf16x8*)(qp + 32 + g * 8);
    }

    float m_run[4], l_run[4];
    f32x4 acc_o[4] = {};
#pragma unroll
    for (int j = 0; j < 4; j++) { m_run[j] = -1e30f; l_run[j] = 0.f; }

    for (int kt = 0; kt <= q64; kt++) {
      gld_lds16(kp0, kd0);
      gld_lds16(kp1, kd1);
      gld_lds16(vp0, vd0);
      gld_lds16(vp1, vd1);
      kp0 += 4096; kp1 += 4096; vp0 += 64; vp1 += 64;
      __syncthreads();   // waits vmcnt(0): staged tile ready

      const bool diag = (kt == q64);        // wave-uniform
      const int cbmax = diag ? wid : 3;

      // S = Q K^T (16 q-rows x 64 kv), exp2-domain scale + causal mask.
      float sv[4][4];
#pragma unroll
      for (int cb = 0; cb < 4; cb++) {
        if (cb > cbmax) continue;
        const int r = cb * 16 + l4;
        const int sw = (r & 7) * 8;
        bf16x8 kb0 = *(const bf16x8*)&Ks[r * 64 + ((g * 8) ^ sw)];
        bf16x8 kb1 = *(const bf16x8*)&Ks[r * 64 + (((g + 4) * 8) ^ sw)];
        f32x4 z = {0.f, 0.f, 0.f, 0.f};
        z = __builtin_amdgcn_mfma_f32_16x16x32_bf16(qf0, kb0, z, 0, 0, 0);
        z = __builtin_amdgcn_mfma_f32_16x16x32_bf16(qf1, kb1, z, 0, 0, 0);
#pragma unroll
        for (int j = 0; j < 4; j++) {
          float s = z[j] * SCL2;
          if (diag && cb == wid) {
            if (cb * 16 + l4 > wid * 16 + 4 * g + j) s = -1e30f;
          }
          sv[cb][j] = s;
        }
      }

      // Online softmax (rows in 16-lane groups; reduce via shfl_xor).
      float mt[4];
#pragma unroll
      for (int j = 0; j < 4; j++) mt[j] = sv[0][j];
#pragma unroll
      for (int cb = 1; cb < 4; cb++) {
        if (cb > cbmax) continue;
#pragma unroll
        for (int j = 0; j < 4; j++) mt[j] = fmaxf(mt[j], sv[cb][j]);
      }
#pragma unroll
      for (int off = 1; off < 16; off <<= 1)
#pragma unroll
        for (int j = 0; j < 4; j++)
          mt[j] = fmaxf(mt[j], __shfl_xor(mt[j], off, 64));
      float alpha[4];
#pragma unroll
      for (int j = 0; j < 4; j++) {
        float mn = fmaxf(m_run[j], mt[j]);
        alpha[j] = fexp2(m_run[j] - mn);
        m_run[j] = mn;
      }
      float ps[4] = {0.f, 0.f, 0.f, 0.f};
#pragma unroll
      for (int cb = 0; cb < 4; cb++) {
        if (cb > cbmax) continue;
#pragma unroll
        for (int j = 0; j < 4; j++) {
          float p = fexp2(sv[cb][j] - m_run[j]);
          sv[cb][j] = p;
          ps[j] += p;
        }
      }
#pragma unroll
      for (int off = 1; off < 16; off <<= 1)
#pragma unroll
        for (int j = 0; j < 4; j++)
          ps[j] += __shfl_xor(ps[j], off, 64);
#pragma unroll
      for (int j = 0; j < 4; j++)
        l_run[j] = l_run[j] * alpha[j] + ps[j];
#pragma unroll
      for (int db = 0; db < 4; db++)
#pragma unroll
        for (int j = 0; j < 4; j++)
          acc_o[db][j] *= alpha[j];

      // P -> LDS (per-wave region) -> A-fragment for PV.
#pragma unroll
      for (int cb = 0; cb < 4; cb++)
#pragma unroll
        for (int j = 0; j < 4; j++)
          Ps[wid][4 * g + j][cb * 16 + l4] = (cb <= cbmax) ? f2bf(sv[cb][j]) : 0;
      asm volatile("s_waitcnt lgkmcnt(0)" ::: "memory");
      __builtin_amdgcn_sched_barrier(0);
      bf16x8 pa0 = *(const bf16x8*)&Ps[wid][l4][g * 8];
      const bool do_hi = !diag || (wid >= 2);   // hi-half P nonzero?
      if (do_hi) {
        bf16x8 pa1 = *(const bf16x8*)&Ps[wid][l4][32 + g * 8];
#pragma unroll
        for (int db = 0; db < 4; db++) {
          const int r = db * 16 + l4;
          const int sw = (r & 7) * 8;
          bf16x8 vb0 = *(const bf16x8*)&Vs[r * 64 + ((g * 8) ^ sw)];
          bf16x8 vb1 = *(const bf16x8*)&Vs[r * 64 + (((g + 4) * 8) ^ sw)];
          acc_o[db] = __builtin_amdgcn_mfma_f32_16x16x32_bf16(pa0, vb0, acc_o[db], 0, 0, 0);
          acc_o[db] = __builtin_amdgcn_mfma_f32_16x16x32_bf16(pa1, vb1, acc_o[db], 0, 0, 0);
        }
      } else {
#pragma unroll
        for (int db = 0; db < 4; db++) {
          const int r = db * 16 + l4;
          const int sw = (r & 7) * 8;
          bf16x8 vb0 = *(const bf16x8*)&Vs[r * 64 + ((g * 8) ^ sw)];
          acc_o[db] = __builtin_amdgcn_mfma_f32_16x16x32_bf16(pa0, vb0, acc_o[db], 0, 0, 0);
        }
      }
      __syncthreads();   // all waves done reading Ks/Vs before next stage
    }

    // Epilogue: normalize and write y[b][t][h*64+d] as bf16.
    unsigned short* yp = yb + ((size_t)(bh >> 4) * TB) * CC + (size_t)(bh & 15) * HD;
    const int qr0 = rbase + 4 * g;
    float inv[4];
#pragma unroll
    for (int j = 0; j < 4; j++) inv[j] = 1.0f / l_run[j];
#pragma unroll
    for (int db = 0; db < 4; db++) {
      const int d = db * 16 + l4;
#pragma unroll
      for (int j = 0; j < 4; j++)
        yp[(size_t)(qr0 + j) * CC + d] = f2bf(acc_o[db][j] * inv[j]);
    }
  }
}

extern "C" void kernel_launch(void* const* d_in, const int* in_sizes, int n_in,
                              void* d_out, int out_size, void* d_ws, size_t ws_size,
                              hipStream_t stream) {
  (void)in_sizes; (void)n_in; (void)out_size; (void)ws_size;
  const float* x  = (const float*)d_in[0];
  const float* fc = (const float*)d_in[1];
  // d_in[2]=attn_mask (tril), d_in[3]=padding_mask (all ones): applied analytically.
  const float* Wq = (const float*)d_in[4];
  const float* bq = (const float*)d_in[5];
  const float* Wk = (const float*)d_in[6];
  const float* bk = (const float*)d_in[7];
  const float* Wv = (const float*)d_in[8];
  const float* bv = (const float*)d_in[9];
  const float* Wp = (const float*)d_in[10];
  const float* bp = (const float*)d_in[11];

  char* ws = (char*)d_ws;
  unsigned short* xb   = (unsigned short*)(ws + 0);          // 8192x1024 bf16 (later reused as yb)
  unsigned short* wqkv = (unsigned short*)(ws + 16777216);   // 3072x1024 bf16
  unsigned short* wp   = (unsigned short*)(ws + 23068672);   // 1024x1024 bf16
  float*          bqkv = (float*)(ws + 25165824);            // 3072 f32
  int*            ctr  = (int*)(ws + 25178112);              // work-steal counter
  unsigned short* qkv  = (unsigned short*)(ws + 25182208);   // 3 x [64][2048][64] bf16
  unsigned short* vT   = qkv + 3 * (size_t)8388608;          // [64][64][2048] bf16
  unsigned short* yb   = xb;

  cvt_f32_bf16<<<(2097152 + 255) / 256, 256, 0, stream>>>(x, xb, 2097152);
  cvt_f32_bf16<<<(262144 + 255) / 256, 256, 0, stream>>>(Wq, wqkv, 262144);
  cvt_f32_bf16<<<(262144 + 255) / 256, 256, 0, stream>>>(Wk, wqkv + 1048576, 262144);
  cvt_f32_bf16<<<(262144 + 255) / 256, 256, 0, stream>>>(Wv, wqkv + 2097152, 262144);
  cvt_f32_bf16<<<(262144 + 255) / 256, 256, 0, stream>>>(Wp, wp, 262144);
  (void)hipMemcpyAsync(bqkv,        bq, 4096, hipMemcpyDeviceToDevice, stream);
  (void)hipMemcpyAsync(bqkv + 1024, bk, 4096, hipMemcpyDeviceToDevice, stream);
  (void)hipMemcpyAsync(bqkv + 2048, bv, 4096, hipMemcpyDeviceToDevice, stream);
  (void)hipMemsetAsync(ctr, 0, 4, stream);

  gemm_bt<1><<<dim3(24, 64), 256, 0, stream>>>(xb, wqkv, bqkv, fc, qkv, BTX, 3072, 1024);
  transpose_v<<<dim3(32, 64), 256, 0, stream>>>(qkv + 2 * (size_t)8388608, vT);
  flash_fwd<<<dim3(1536), 256, 0, stream>>>(qkv, qkv + (size_t)8388608, vT, yb, ctr);
  gemm_bt<0><<<dim3(8, 64), 256, 0, stream>>>(yb, wp, bp, nullptr, (float*)d_out, BTX, 1024, 1024);
}

// Round 7
// 294.379 us; speedup vs baseline: 1.3749x; 1.0387x over previous
//
#include <hip/hip_runtime.h>
#include <hip/hip_bf16.h>

#define TB 2048
#define CC 1024
#define NH 16
#define HD 64
#define NB 4
#define BHX (NB*NH)    // 64
#define BTX (NB*TB)    // 8192
#define NITEMS 2048

typedef __attribute__((ext_vector_type(8))) short bf16x8;
typedef __attribute__((ext_vector_type(4))) float f32x4;
typedef __attribute__((ext_vector_type(4))) unsigned short us4;

__device__ __forceinline__ unsigned short f2bf(float f) {
  union { float f; unsigned u; } v; v.f = f;
  unsigned r = v.u + 0x7fffu + ((v.u >> 16) & 1u);
  return (unsigned short)(r >> 16);
}
__device__ __forceinline__ float bf2f(unsigned short u) {
  union { unsigned u; float f; } v; v.u = ((unsigned)u) << 16;
  return v.f;
}
__device__ __forceinline__ float fexp2(float x) {
  return __builtin_amdgcn_exp2f(x);   // v_exp_f32 (2^x)
}

__device__ __forceinline__ void gld_lds16(const void* g, void* l) {
  __builtin_amdgcn_global_load_lds(
      (const __attribute__((address_space(1))) unsigned*)g,
      (__attribute__((address_space(3))) unsigned*)l, 16, 0, 0);
}

__global__ void cvt_f32_bf16(const float* __restrict__ src,
                             unsigned short* __restrict__ dst, int n4) {
  int i = blockIdx.x * blockDim.x + threadIdx.x;
  if (i >= n4) return;
  f32x4 v = ((const f32x4*)src)[i];
  us4 o;
#pragma unroll
  for (int j = 0; j < 4; j++) o[j] = f2bf(v[j]);
  ((us4*)dst)[i] = o;
}

// C[i][n] = sum_k A[i][k]*Bw[n][k] + bias[n].
// MODE 0: f32 output row-major [M][N] (final projection).
// MODE 1: bf16 output scattered to qkv[part][bh][t][d] layout, with RoPE
//         applied to parts 0,1 (q,k) via shfl partner exchange.
template <int MODE>
__global__ __launch_bounds__(256) void gemm_bt(
    const unsigned short* __restrict__ A, const unsigned short* __restrict__ Bw,
    const float* __restrict__ bias, const float* __restrict__ fcg,
    void* __restrict__ Cout, int M, int N, int K)
{
  __shared__ __align__(16) unsigned short As[128 * 32];
  __shared__ __align__(16) unsigned short Bs[128 * 32];
  int tid = threadIdx.x;
  int lane = tid & 63, wid = tid >> 6;
  int g = lane >> 4, l4 = lane & 15;
  int wr = wid >> 1, wc = wid & 1;
  int brow = blockIdx.y * 128, bcol = blockIdx.x * 128;

  const unsigned short* ap = A + (size_t)(brow + (tid >> 2)) * K + (tid & 3) * 8;
  const unsigned short* bp_ = Bw + (size_t)(bcol + (tid >> 2)) * K + (tid & 3) * 8;
  const size_t rstep = (size_t)64 * K;
  unsigned short* asl = As + tid * 8;
  unsigned short* bsl = Bs + tid * 8;

  f32x4 acc[4][4] = {};

  for (int k0 = 0; k0 < K; k0 += 32) {
    gld_lds16(ap, asl);
    gld_lds16(ap + rstep, asl + 2048);
    gld_lds16(bp_, bsl);
    gld_lds16(bp_ + rstep, bsl + 2048);
    ap += 32; bp_ += 32;
    __syncthreads();
    bf16x8 af[4], bfr[4];
#pragma unroll
    for (int i = 0; i < 4; i++)
      af[i] = *(const bf16x8*)&As[(wr * 64 + i * 16 + l4) * 32 + g * 8];
#pragma unroll
    for (int i = 0; i < 4; i++)
      bfr[i] = *(const bf16x8*)&Bs[(wc * 64 + i * 16 + l4) * 32 + g * 8];
#pragma unroll
    for (int i = 0; i < 4; i++)
#pragma unroll
      for (int j = 0; j < 4; j++)
        acc[i][j] = __builtin_amdgcn_mfma_f32_16x16x32_bf16(af[i], bfr[j], acc[i][j], 0, 0, 0);
    __syncthreads();
  }

#pragma unroll
  for (int i = 0; i < 4; i++) {
    int grow0 = brow + wr * 64 + i * 16 + 4 * g;
#pragma unroll
    for (int j = 0; j < 4; j++) {
      int gcol = bcol + wc * 64 + j * 16 + l4;
      float bv = bias[gcol];
      if (MODE == 0) {
        float* out = (float*)Cout;
#pragma unroll
        for (int r = 0; r < 4; r++)
          out[(size_t)(grow0 + r) * N + gcol] = acc[i][j][r] + bv;
      } else {
        unsigned short* out = (unsigned short*)Cout;
        int part = gcol >> 10;
        int c = gcol & 1023;
        int h = c >> 6, d = c & 63;
        int dbase = d & ~1;
        float sgn = (d & 1) ? 1.f : -1.f;
        bool isqk = (part < 2);   // uniform across the l4/l4^1 pair
#pragma unroll
        for (int r = 0; r < 4; r++) {
          int grow = grow0 + r;
          int b = grow >> 11, t = grow & 2047;
          float v = acc[i][j][r] + bv;
          float w = __shfl_xor(v, 1, 64);  // partner dim's value
          float o = v;
          if (isqk) {
            float cth = fcg[(size_t)t * 64 + dbase];
            float sth = fcg[(size_t)t * 64 + dbase + 1];
            o = v * cth + sgn * w * sth;
          }
          size_t dst = (size_t)part * ((size_t)BHX * TB * HD)
                     + ((size_t)(b * NH + h) * TB + t) * HD + d;
          out[dst] = f2bf(o);
        }
      }
    }
  }
}

// v [bh][T][64] -> vT [bh][64][T], 64x64 tiles. 256 threads, 2 chunks each way.
__global__ void transpose_v(const unsigned short* __restrict__ v,
                            unsigned short* __restrict__ vT) {
  int bh = blockIdx.y, t0 = blockIdx.x * 64;
  __shared__ __align__(16) unsigned short tile[64][72];
  int tid = threadIdx.x;
#pragma unroll
  for (int s = 0; s < 2; s++) {
    int cid = tid + 256 * s;
    int r = cid >> 3, c8 = (cid & 7) * 8;
    bf16x8 val = *(const bf16x8*)(v + ((size_t)bh * TB + t0 + r) * HD + c8);
    *(bf16x8*)&tile[r][c8] = val;
  }
  __syncthreads();
#pragma unroll
  for (int s = 0; s < 2; s++) {
    int cid = tid + 256 * s;
    int rr = cid >> 3, cc = (cid & 7) * 8;
    bf16x8 o;
#pragma unroll
    for (int i = 0; i < 8; i++) o[i] = (short)tile[cc + i][rr];
    *(bf16x8*)(vT + ((size_t)bh * HD + rr) * TB + t0 + cc) = o;
  }
}

// Flash attention fwd, causal. Work-stealing over 2048 items (bh, q64):
// 64 q-rows per item, 4 waves x 16 rows, KV tiles of 64. Heavy items first.
// K pre-roped, V^T pre-transposed; staged via global_load_lds with
// XOR-swizzled source so ds_read_b128 is spread across banks.
// launch_bounds(256,8): force VGPR<=64 so 6 blocks/CU fit (LDS-capped).
__global__ __launch_bounds__(256, 8) void flash_fwd(
    const unsigned short* __restrict__ q, const unsigned short* __restrict__ k,
    const unsigned short* __restrict__ vT, unsigned short* __restrict__ yb,
    int* __restrict__ ctr)
{
  __shared__ __align__(16) unsigned short Ks[64 * 64];  // linear, swz content
  __shared__ __align__(16) unsigned short Vs[64 * 64];  // linear, swz content
  __shared__ __align__(16) unsigned short Ps[4][16][72];
  __shared__ int s_item;

  const int tid = threadIdx.x, wid = tid >> 6, lane = tid & 63;
  const int g = lane >> 4, l4 = lane & 15;

  // fixed staging geometry: 2 passes x 16B per thread per tile
  const int off0 = tid << 4;                       // bytes in 4KB pass 0
  const int row0 = off0 >> 7, sc0 = ((off0 >> 4) & 7) ^ (row0 & 7);
  const int off1 = off0 + 4096;
  const int row1 = off1 >> 7, sc1 = ((off1 >> 4) & 7) ^ (row1 & 7);
  unsigned short* kd0 = Ks + (off0 >> 1);
  unsigned short* kd1 = Ks + (off1 >> 1);
  unsigned short* vd0 = Vs + (off0 >> 1);
  unsigned short* vd1 = Vs + (off1 >> 1);
  // per-lane invariant global element-offsets
  const int koff0 = (row0 << 6) + (sc0 << 3);
  const int koff1 = (row1 << 6) + (sc1 << 3);
  const int voff0 = (row0 << 11) + (sc0 << 3);
  const int voff1 = (row1 << 11) + (sc1 << 3);

  const float SCL2 = 0.18033688011112042f;  // 1/8 * log2(e)

  for (;;) {
    __syncthreads();
    if (tid == 0) s_item = atomicAdd(ctr, 1);
    __syncthreads();
    const int w = s_item;
    if (w >= NITEMS) break;
    const int q64 = 31 - (w >> 6), bh = w & 63;
    const int rbase = q64 * 64 + wid * 16;   // wave's absolute q-row base

    const unsigned short* kb = k  + ((size_t)bh << 17);  // bh*T*HD
    const unsigned short* vb = vT + ((size_t)bh << 17);  // bh*HD*T

    // Q fragments (pre-roped by GEMM epilogue)
    bf16x8 qf0, qf1;
    {
      const unsigned short* qp = kb - ((size_t)1 << 23) + ((size_t)(rbase + l4) << 6);
      // q = k - 64*2048*64 elements (q part precedes k in qkv buffer)
      qf0 = *(const bf16x8*)(qp + g * 8);
      qf1 = *(const bf16x8*)(qp + 32 + g * 8);
    }

    float m_run[4], l_run[4];
    f32x4 acc_o[4] = {};
#pragma unroll
    for (int j = 0; j < 4; j++) { m_run[j] = -1e30f; l_run[j] = 0.f; }

    for (int kt = 0; kt <= q64; kt++) {
      const int kadd = kt << 12;   // 4096 elements per K tile
      const int vadd = kt << 6;    // 64 elements per V^T tile column-step
      gld_lds16(kb + koff0 + kadd, kd0);
      gld_lds16(kb + koff1 + kadd, kd1);
      gld_lds16(vb + voff0 + vadd, vd0);
      gld_lds16(vb + voff1 + vadd, vd1);
      __syncthreads();   // waits vmcnt(0): staged tile ready

      // S = Q K^T (16 q-rows x 64 kv), exp2-domain scale + causal mask.
      float sv[4][4];
#pragma unroll
      for (int cb = 0; cb < 4; cb++) {
        const int r = cb * 16 + l4;
        const int sw = (r & 7) * 8;
        bf16x8 kb0 = *(const bf16x8*)&Ks[r * 64 + ((g * 8) ^ sw)];
        bf16x8 kb1 = *(const bf16x8*)&Ks[r * 64 + (((g + 4) * 8) ^ sw)];
        f32x4 z = {0.f, 0.f, 0.f, 0.f};
        z = __builtin_amdgcn_mfma_f32_16x16x32_bf16(qf0, kb0, z, 0, 0, 0);
        z = __builtin_amdgcn_mfma_f32_16x16x32_bf16(qf1, kb1, z, 0, 0, 0);
#pragma unroll
        for (int j = 0; j < 4; j++)
          sv[cb][j] = z[j] * SCL2;
      }
      if (kt == q64) {             // wave-uniform diagonal tile: causal mask
        const int rq = wid * 16 + 4 * g;
#pragma unroll
        for (int cb = 0; cb < 4; cb++)
#pragma unroll
          for (int j = 0; j < 4; j++)
            if (cb * 16 + l4 > rq + j) sv[cb][j] = -1e30f;
      }

      // Online softmax (rows in 16-lane groups; reduce via shfl_xor).
      float mt[4];
#pragma unroll
      for (int j = 0; j < 4; j++)
        mt[j] = fmaxf(fmaxf(sv[0][j], sv[1][j]), fmaxf(sv[2][j], sv[3][j]));
#pragma unroll
      for (int off = 1; off < 16; off <<= 1)
#pragma unroll
        for (int j = 0; j < 4; j++)
          mt[j] = fmaxf(mt[j], __shfl_xor(mt[j], off, 64));
      float alpha[4];
#pragma unroll
      for (int j = 0; j < 4; j++) {
        float mn = fmaxf(m_run[j], mt[j]);
        alpha[j] = fexp2(m_run[j] - mn);
        m_run[j] = mn;
      }
      float ps[4] = {0.f, 0.f, 0.f, 0.f};
#pragma unroll
      for (int cb = 0; cb < 4; cb++)
#pragma unroll
        for (int j = 0; j < 4; j++) {
          float p = fexp2(sv[cb][j] - m_run[j]);
          sv[cb][j] = p;
          ps[j] += p;
        }
#pragma unroll
      for (int off = 1; off < 16; off <<= 1)
#pragma unroll
        for (int j = 0; j < 4; j++)
          ps[j] += __shfl_xor(ps[j], off, 64);
#pragma unroll
      for (int j = 0; j < 4; j++)
        l_run[j] = l_run[j] * alpha[j] + ps[j];
#pragma unroll
      for (int db = 0; db < 4; db++)
#pragma unroll
        for (int j = 0; j < 4; j++)
          acc_o[db][j] *= alpha[j];

      // P -> LDS (per-wave region) -> A-fragment for PV.
#pragma unroll
      for (int cb = 0; cb < 4; cb++)
#pragma unroll
        for (int j = 0; j < 4; j++)
          Ps[wid][4 * g + j][cb * 16 + l4] = f2bf(sv[cb][j]);
      asm volatile("s_waitcnt lgkmcnt(0)" ::: "memory");
      __builtin_amdgcn_sched_barrier(0);
      bf16x8 pa0 = *(const bf16x8*)&Ps[wid][l4][g * 8];
      bf16x8 pa1 = *(const bf16x8*)&Ps[wid][l4][32 + g * 8];
#pragma unroll
      for (int db = 0; db < 4; db++) {
        const int r = db * 16 + l4;
        const int sw = (r & 7) * 8;
        bf16x8 vb0 = *(const bf16x8*)&Vs[r * 64 + ((g * 8) ^ sw)];
        bf16x8 vb1 = *(const bf16x8*)&Vs[r * 64 + (((g + 4) * 8) ^ sw)];
        acc_o[db] = __builtin_amdgcn_mfma_f32_16x16x32_bf16(pa0, vb0, acc_o[db], 0, 0, 0);
        acc_o[db] = __builtin_amdgcn_mfma_f32_16x16x32_bf16(pa1, vb1, acc_o[db], 0, 0, 0);
      }
      __syncthreads();   // all waves done reading Ks/Vs before next stage
    }

    // Epilogue: normalize and write y[b][t][h*64+d] as bf16.
    unsigned short* yp = yb + ((size_t)(bh >> 4) * TB) * CC + (size_t)(bh & 15) * HD;
    const int qr0 = rbase + 4 * g;
    float inv[4];
#pragma unroll
    for (int j = 0; j < 4; j++) inv[j] = 1.0f / l_run[j];
#pragma unroll
    for (int db = 0; db < 4; db++) {
      const int d = db * 16 + l4;
#pragma unroll
      for (int j = 0; j < 4; j++)
        yp[(size_t)(qr0 + j) * CC + d] = f2bf(acc_o[db][j] * inv[j]);
    }
  }
}

extern "C" void kernel_launch(void* const* d_in, const int* in_sizes, int n_in,
                              void* d_out, int out_size, void* d_ws, size_t ws_size,
                              hipStream_t stream) {
  (void)in_sizes; (void)n_in; (void)out_size; (void)ws_size;
  const float* x  = (const float*)d_in[0];
  const float* fc = (const float*)d_in[1];
  // d_in[2]=attn_mask (tril), d_in[3]=padding_mask (all ones): applied analytically.
  const float* Wq = (const float*)d_in[4];
  const float* bq = (const float*)d_in[5];
  const float* Wk = (const float*)d_in[6];
  const float* bk = (const float*)d_in[7];
  const float* Wv = (const float*)d_in[8];
  const float* bv = (const float*)d_in[9];
  const float* Wp = (const float*)d_in[10];
  const float* bp = (const float*)d_in[11];

  char* ws = (char*)d_ws;
  unsigned short* xb   = (unsigned short*)(ws + 0);          // 8192x1024 bf16 (later reused as yb)
  unsigned short* wqkv = (unsigned short*)(ws + 16777216);   // 3072x1024 bf16
  unsigned short* wp   = (unsigned short*)(ws + 23068672);   // 1024x1024 bf16
  float*          bqkv = (float*)(ws + 25165824);            // 3072 f32
  int*            ctr  = (int*)(ws + 25178112);              // work-steal counter
  unsigned short* qkv  = (unsigned short*)(ws + 25182208);   // 3 x [64][2048][64] bf16
  unsigned short* vT   = qkv + 3 * (size_t)8388608;          // [64][64][2048] bf16
  unsigned short* yb   = xb;

  cvt_f32_bf16<<<(2097152 + 255) / 256, 256, 0, stream>>>(x, xb, 2097152);
  cvt_f32_bf16<<<(262144 + 255) / 256, 256, 0, stream>>>(Wq, wqkv, 262144);
  cvt_f32_bf16<<<(262144 + 255) / 256, 256, 0, stream>>>(Wk, wqkv + 1048576, 262144);
  cvt_f32_bf16<<<(262144 + 255) / 256, 256, 0, stream>>>(Wv, wqkv + 2097152, 262144);
  cvt_f32_bf16<<<(262144 + 255) / 256, 256, 0, stream>>>(Wp, wp, 262144);
  (void)hipMemcpyAsync(bqkv,        bq, 4096, hipMemcpyDeviceToDevice, stream);
  (void)hipMemcpyAsync(bqkv + 1024, bk, 4096, hipMemcpyDeviceToDevice, stream);
  (void)hipMemcpyAsync(bqkv + 2048, bv, 4096, hipMemcpyDeviceToDevice, stream);
  (void)hipMemsetAsync(ctr, 0, 4, stream);

  gemm_bt<1><<<dim3(24, 64), 256, 0, stream>>>(xb, wqkv, bqkv, fc, qkv, BTX, 3072, 1024);
  transpose_v<<<dim3(32, 64), 256, 0, stream>>>(qkv + 2 * (size_t)8388608, vT);
  flash_fwd<<<dim3(1536), 256, 0, stream>>>(qkv, qkv + (size_t)8388608, vT, yb, ctr);
  gemm_bt<0><<<dim3(8, 64), 256, 0, stream>>>(yb, wp, bp, nullptr, (float*)d_out, BTX, 1024, 1024);
}

// Round 8
// 283.702 us; speedup vs baseline: 1.4266x; 1.0376x over previous
//
#include <hip/hip_runtime.h>
#include <hip/hip_bf16.h>

#define TB 2048
#define CC 1024
#define NH 16
#define HD 64
#define NB 4
#define BHX (NB*NH)    // 64
#define BTX (NB*TB)    // 8192
#define NITEMS 2048

typedef __attribute__((ext_vector_type(8))) short bf16x8;
typedef __attribute__((ext_vector_type(4))) float f32x4;
typedef __attribute__((ext_vector_type(4))) unsigned short us4;

__device__ __forceinline__ unsigned short f2bf(float f) {
  union { float f; unsigned u; } v; v.f = f;
  unsigned r = v.u + 0x7fffu + ((v.u >> 16) & 1u);
  return (unsigned short)(r >> 16);
}
__device__ __forceinline__ float bf2f(unsigned short u) {
  union { unsigned u; float f; } v; v.u = ((unsigned)u) << 16;
  return v.f;
}
__device__ __forceinline__ float fexp2(float x) {
  return __builtin_amdgcn_exp2f(x);   // v_exp_f32 (2^x)
}

__device__ __forceinline__ void gld_lds16(const void* g, void* l) {
  __builtin_amdgcn_global_load_lds(
      (const __attribute__((address_space(1))) unsigned*)g,
      (__attribute__((address_space(3))) unsigned*)l, 16, 0, 0);
}

__global__ void cvt_f32_bf16(const float* __restrict__ src,
                             unsigned short* __restrict__ dst, int n4) {
  int i = blockIdx.x * blockDim.x + threadIdx.x;
  if (i >= n4) return;
  f32x4 v = ((const f32x4*)src)[i];
  us4 o;
#pragma unroll
  for (int j = 0; j < 4; j++) o[j] = f2bf(v[j]);
  ((us4*)dst)[i] = o;
}

// C[i][n] = sum_k A[i][k]*Bw[n][k] + bias[n].
// MODE 0: f32 output row-major [M][N] (final projection).
// MODE 1: bf16 output scattered to qkv[part][bh][t][d] layout, with RoPE
//         applied to parts 0,1 (q,k) via shfl partner exchange.
template <int MODE>
__global__ __launch_bounds__(256) void gemm_bt(
    const unsigned short* __restrict__ A, const unsigned short* __restrict__ Bw,
    const float* __restrict__ bias, const float* __restrict__ fcg,
    void* __restrict__ Cout, int M, int N, int K)
{
  __shared__ __align__(16) unsigned short As[128 * 32];
  __shared__ __align__(16) unsigned short Bs[128 * 32];
  int tid = threadIdx.x;
  int lane = tid & 63, wid = tid >> 6;
  int g = lane >> 4, l4 = lane & 15;
  int wr = wid >> 1, wc = wid & 1;
  int brow = blockIdx.y * 128, bcol = blockIdx.x * 128;

  const unsigned short* ap = A + (size_t)(brow + (tid >> 2)) * K + (tid & 3) * 8;
  const unsigned short* bp_ = Bw + (size_t)(bcol + (tid >> 2)) * K + (tid & 3) * 8;
  const size_t rstep = (size_t)64 * K;
  unsigned short* asl = As + tid * 8;
  unsigned short* bsl = Bs + tid * 8;

  f32x4 acc[4][4] = {};

  for (int k0 = 0; k0 < K; k0 += 32) {
    gld_lds16(ap, asl);
    gld_lds16(ap + rstep, asl + 2048);
    gld_lds16(bp_, bsl);
    gld_lds16(bp_ + rstep, bsl + 2048);
    ap += 32; bp_ += 32;
    __syncthreads();
    bf16x8 af[4], bfr[4];
#pragma unroll
    for (int i = 0; i < 4; i++)
      af[i] = *(const bf16x8*)&As[(wr * 64 + i * 16 + l4) * 32 + g * 8];
#pragma unroll
    for (int i = 0; i < 4; i++)
      bfr[i] = *(const bf16x8*)&Bs[(wc * 64 + i * 16 + l4) * 32 + g * 8];
#pragma unroll
    for (int i = 0; i < 4; i++)
#pragma unroll
      for (int j = 0; j < 4; j++)
        acc[i][j] = __builtin_amdgcn_mfma_f32_16x16x32_bf16(af[i], bfr[j], acc[i][j], 0, 0, 0);
    __syncthreads();
  }

#pragma unroll
  for (int i = 0; i < 4; i++) {
    int grow0 = brow + wr * 64 + i * 16 + 4 * g;
#pragma unroll
    for (int j = 0; j < 4; j++) {
      int gcol = bcol + wc * 64 + j * 16 + l4;
      float bv = bias[gcol];
      if (MODE == 0) {
        float* out = (float*)Cout;
#pragma unroll
        for (int r = 0; r < 4; r++)
          out[(size_t)(grow0 + r) * N + gcol] = acc[i][j][r] + bv;
      } else {
        unsigned short* out = (unsigned short*)Cout;
        int part = gcol >> 10;
        int c = gcol & 1023;
        int h = c >> 6, d = c & 63;
        int dbase = d & ~1;
        float sgn = (d & 1) ? 1.f : -1.f;
        bool isqk = (part < 2);   // uniform across the l4/l4^1 pair
#pragma unroll
        for (int r = 0; r < 4; r++) {
          int grow = grow0 + r;
          int b = grow >> 11, t = grow & 2047;
          float v = acc[i][j][r] + bv;
          float w = __shfl_xor(v, 1, 64);  // partner dim's value
          float o = v;
          if (isqk) {
            float cth = fcg[(size_t)t * 64 + dbase];
            float sth = fcg[(size_t)t * 64 + dbase + 1];
            o = v * cth + sgn * w * sth;
          }
          size_t dst = (size_t)part * ((size_t)BHX * TB * HD)
                     + ((size_t)(b * NH + h) * TB + t) * HD + d;
          out[dst] = f2bf(o);
        }
      }
    }
  }
}

// v [bh][T][64] -> vT [bh][64][T], 64x64 tiles. 256 threads, 2 chunks each way.
__global__ void transpose_v(const unsigned short* __restrict__ v,
                            unsigned short* __restrict__ vT) {
  int bh = blockIdx.y, t0 = blockIdx.x * 64;
  __shared__ __align__(16) unsigned short tile[64][72];
  int tid = threadIdx.x;
#pragma unroll
  for (int s = 0; s < 2; s++) {
    int cid = tid + 256 * s;
    int r = cid >> 3, c8 = (cid & 7) * 8;
    bf16x8 val = *(const bf16x8*)(v + ((size_t)bh * TB + t0 + r) * HD + c8);
    *(bf16x8*)&tile[r][c8] = val;
  }
  __syncthreads();
#pragma unroll
  for (int s = 0; s < 2; s++) {
    int cid = tid + 256 * s;
    int rr = cid >> 3, cc = (cid & 7) * 8;
    bf16x8 o;
#pragma unroll
    for (int i = 0; i < 8; i++) o[i] = (short)tile[cc + i][rr];
    *(bf16x8*)(vT + ((size_t)bh * HD + rr) * TB + t0 + cc) = o;
  }
}

// Flash attention fwd, causal. Work-stealing over 2048 items (bh, q64):
// 64 q-rows per item, 4 waves x 16 rows, KV tiles of 64. Heavy items first.
// K pre-roped, V^T pre-transposed; staged via global_load_lds with
// XOR-swizzled source. DOUBLE-BUFFERED: tile t+1's loads are issued before
// computing tile t, so the auto vmcnt(0) at the single end-of-tile barrier
// waits on loads that flew during the whole compute phase.
__global__ __launch_bounds__(256, 4) void flash_fwd(
    const unsigned short* __restrict__ q, const unsigned short* __restrict__ k,
    const unsigned short* __restrict__ vT, unsigned short* __restrict__ yb,
    int* __restrict__ ctr)
{
  __shared__ __align__(16) unsigned short Ks[2][4096];  // linear, swz content
  __shared__ __align__(16) unsigned short Vs[2][4096];
  __shared__ __align__(16) unsigned short Ps[4][16][72];
  __shared__ int s_item;

  const int tid = threadIdx.x, wid = tid >> 6, lane = tid & 63;
  const int g = lane >> 4, l4 = lane & 15;

  // fixed staging geometry: 2 passes x 16B per thread per tile
  const int off0 = tid << 4;                       // bytes in 4KB pass 0
  const int row0 = off0 >> 7, sc0 = ((off0 >> 4) & 7) ^ (row0 & 7);
  const int off1 = off0 + 4096;
  const int row1 = off1 >> 7, sc1 = ((off1 >> 4) & 7) ^ (row1 & 7);
  // per-lane invariant global element-offsets
  const int koff0 = (row0 << 6) + (sc0 << 3);
  const int koff1 = (row1 << 6) + (sc1 << 3);
  const int voff0 = (row0 << 11) + (sc0 << 3);
  const int voff1 = (row1 << 11) + (sc1 << 3);

  const float SCL2 = 0.18033688011112042f;  // 1/8 * log2(e)

  for (;;) {
    __syncthreads();
    if (tid == 0) s_item = atomicAdd(ctr, 1);
    __syncthreads();
    const int w = s_item;
    if (w >= NITEMS) break;
    const int q64 = 31 - (w >> 6), bh = w & 63;
    const int rbase = q64 * 64 + wid * 16;   // wave's absolute q-row base

    const unsigned short* kb = k  + ((size_t)bh << 17);  // bh*T*HD
    const unsigned short* vb = vT + ((size_t)bh << 17);  // bh*HD*T

    // Q fragments (pre-roped by GEMM epilogue)
    bf16x8 qf0, qf1;
    {
      const unsigned short* qp = q + (((size_t)bh * TB + rbase + l4) << 6);
      qf0 = *(const bf16x8*)(qp + g * 8);
      qf1 = *(const bf16x8*)(qp + 32 + g * 8);
    }

    float m_run[4], l_run[4];
    f32x4 acc_o[4] = {};
#pragma unroll
    for (int j = 0; j < 4; j++) { m_run[j] = -1e30f; l_run[j] = 0.f; }

    // Prologue: stage tile 0 into buf 0.
    gld_lds16(kb + koff0, &Ks[0][off0 >> 1]);
    gld_lds16(kb + koff1, &Ks[0][(off1 - 4096) >> 1 | 2048]);
    gld_lds16(vb + voff0, &Vs[0][off0 >> 1]);
    gld_lds16(vb + voff1, &Vs[0][off1 >> 1]);
    __syncthreads();   // auto vmcnt(0): tile 0 ready

    for (int kt = 0; kt <= q64; kt++) {
      const int cur = kt & 1;
      if (kt < q64) {   // issue next tile's loads; they fly during compute
        const int kadd = (kt + 1) << 12;   // 4096 elements per K tile
        const int vadd = (kt + 1) << 6;    // 64 elements per V^T column-step
        gld_lds16(kb + koff0 + kadd, &Ks[cur ^ 1][off0 >> 1]);
        gld_lds16(kb + koff1 + kadd, &Ks[cur ^ 1][off1 >> 1]);
        gld_lds16(vb + voff0 + vadd, &Vs[cur ^ 1][off0 >> 1]);
        gld_lds16(vb + voff1 + vadd, &Vs[cur ^ 1][off1 >> 1]);
      }
      const unsigned short* Kc = Ks[cur];
      const unsigned short* Vc = Vs[cur];

      // S = Q K^T (16 q-rows x 64 kv), exp2-domain scale + causal mask.
      float sv[4][4];
#pragma unroll
      for (int cb = 0; cb < 4; cb++) {
        const int r = cb * 16 + l4;
        const int sw = (r & 7) * 8;
        bf16x8 kb0 = *(const bf16x8*)&Kc[r * 64 + ((g * 8) ^ sw)];
        bf16x8 kb1 = *(const bf16x8*)&Kc[r * 64 + (((g + 4) * 8) ^ sw)];
        f32x4 z = {0.f, 0.f, 0.f, 0.f};
        z = __builtin_amdgcn_mfma_f32_16x16x32_bf16(qf0, kb0, z, 0, 0, 0);
        z = __builtin_amdgcn_mfma_f32_16x16x32_bf16(qf1, kb1, z, 0, 0, 0);
#pragma unroll
        for (int j = 0; j < 4; j++)
          sv[cb][j] = z[j] * SCL2;
      }
      if (kt == q64) {             // wave-uniform diagonal tile: causal mask
        const int rq = wid * 16 + 4 * g;
#pragma unroll
        for (int cb = 0; cb < 4; cb++)
#pragma unroll
          for (int j = 0; j < 4; j++)
            if (cb * 16 + l4 > rq + j) sv[cb][j] = -1e30f;
      }

      // Online softmax (rows in 16-lane groups; reduce via shfl_xor).
      float mt[4];
#pragma unroll
      for (int j = 0; j < 4; j++)
        mt[j] = fmaxf(fmaxf(sv[0][j], sv[1][j]), fmaxf(sv[2][j], sv[3][j]));
#pragma unroll
      for (int off = 1; off < 16; off <<= 1)
#pragma unroll
        for (int j = 0; j < 4; j++)
          mt[j] = fmaxf(mt[j], __shfl_xor(mt[j], off, 64));
      float alpha[4];
#pragma unroll
      for (int j = 0; j < 4; j++) {
        float mn = fmaxf(m_run[j], mt[j]);
        alpha[j] = fexp2(m_run[j] - mn);
        m_run[j] = mn;
      }
      float ps[4] = {0.f, 0.f, 0.f, 0.f};
#pragma unroll
      for (int cb = 0; cb < 4; cb++)
#pragma unroll
        for (int j = 0; j < 4; j++) {
          float p = fexp2(sv[cb][j] - m_run[j]);
          sv[cb][j] = p;
          ps[j] += p;
        }
#pragma unroll
      for (int off = 1; off < 16; off <<= 1)
#pragma unroll
        for (int j = 0; j < 4; j++)
          ps[j] += __shfl_xor(ps[j], off, 64);
#pragma unroll
      for (int j = 0; j < 4; j++)
        l_run[j] = l_run[j] * alpha[j] + ps[j];
#pragma unroll
      for (int db = 0; db < 4; db++)
#pragma unroll
        for (int j = 0; j < 4; j++)
          acc_o[db][j] *= alpha[j];

      // P -> LDS (per-wave region) -> A-fragment for PV.
#pragma unroll
      for (int cb = 0; cb < 4; cb++)
#pragma unroll
        for (int j = 0; j < 4; j++)
          Ps[wid][4 * g + j][cb * 16 + l4] = f2bf(sv[cb][j]);
      asm volatile("s_waitcnt lgkmcnt(0)" ::: "memory");
      __builtin_amdgcn_sched_barrier(0);
      bf16x8 pa0 = *(const bf16x8*)&Ps[wid][l4][g * 8];
      bf16x8 pa1 = *(const bf16x8*)&Ps[wid][l4][32 + g * 8];
#pragma unroll
      for (int db = 0; db < 4; db++) {
        const int r = db * 16 + l4;
        const int sw = (r & 7) * 8;
        bf16x8 vb0 = *(const bf16x8*)&Vc[r * 64 + ((g * 8) ^ sw)];
        bf16x8 vb1 = *(const bf16x8*)&Vc[r * 64 + (((g + 4) * 8) ^ sw)];
        acc_o[db] = __builtin_amdgcn_mfma_f32_16x16x32_bf16(pa0, vb0, acc_o[db], 0, 0, 0);
        acc_o[db] = __builtin_amdgcn_mfma_f32_16x16x32_bf16(pa1, vb1, acc_o[db], 0, 0, 0);
      }
      // Single barrier per tile: auto vmcnt(0) waits next tile's DMA (already
      // flown during compute); auto lgkmcnt(0) covers all waves' LDS reads.
      __syncthreads();
    }

    // Epilogue: normalize and write y[b][t][h*64+d] as bf16.
    unsigned short* yp = yb + ((size_t)(bh >> 4) * TB) * CC + (size_t)(bh & 15) * HD;
    const int qr0 = rbase + 4 * g;
    float inv[4];
#pragma unroll
    for (int j = 0; j < 4; j++) inv[j] = 1.0f / l_run[j];
#pragma unroll
    for (int db = 0; db < 4; db++) {
      const int d = db * 16 + l4;
#pragma unroll
      for (int j = 0; j < 4; j++)
        yp[(size_t)(qr0 + j) * CC + d] = f2bf(acc_o[db][j] * inv[j]);
    }
  }
}

extern "C" void kernel_launch(void* const* d_in, const int* in_sizes, int n_in,
                              void* d_out, int out_size, void* d_ws, size_t ws_size,
                              hipStream_t stream) {
  (void)in_sizes; (void)n_in; (void)out_size; (void)ws_size;
  const float* x  = (const float*)d_in[0];
  const float* fc = (const float*)d_in[1];
  // d_in[2]=attn_mask (tril), d_in[3]=padding_mask (all ones): applied analytically.
  const float* Wq = (const float*)d_in[4];
  const float* bq = (const float*)d_in[5];
  const float* Wk = (const float*)d_in[6];
  const float* bk = (const float*)d_in[7];
  const float* Wv = (const float*)d_in[8];
  const float* bv = (const float*)d_in[9];
  const float* Wp = (const float*)d_in[10];
  const float* bp = (const float*)d_in[11];

  char* ws = (char*)d_ws;
  unsigned short* xb   = (unsigned short*)(ws + 0);          // 8192x1024 bf16 (later reused as yb)
  unsigned short* wqkv = (unsigned short*)(ws + 16777216);   // 3072x1024 bf16
  unsigned short* wp   = (unsigned short*)(ws + 23068672);   // 1024x1024 bf16
  float*          bqkv = (float*)(ws + 25165824);            // 3072 f32
  int*            ctr  = (int*)(ws + 25178112);              // work-steal counter
  unsigned short* qkv  = (unsigned short*)(ws + 25182208);   // 3 x [64][2048][64] bf16
  unsigned short* vT   = qkv + 3 * (size_t)8388608;          // [64][64][2048] bf16
  unsigned short* yb   = xb;

  cvt_f32_bf16<<<(2097152 + 255) / 256, 256, 0, stream>>>(x, xb, 2097152);
  cvt_f32_bf16<<<(262144 + 255) / 256, 256, 0, stream>>>(Wq, wqkv, 262144);
  cvt_f32_bf16<<<(262144 + 255) / 256, 256, 0, stream>>>(Wk, wqkv + 1048576, 262144);
  cvt_f32_bf16<<<(262144 + 255) / 256, 256, 0, stream>>>(Wv, wqkv + 2097152, 262144);
  cvt_f32_bf16<<<(262144 + 255) / 256, 256, 0, stream>>>(Wp, wp, 262144);
  (void)hipMemcpyAsync(bqkv,        bq, 4096, hipMemcpyDeviceToDevice, stream);
  (void)hipMemcpyAsync(bqkv + 1024, bk, 4096, hipMemcpyDeviceToDevice, stream);
  (void)hipMemcpyAsync(bqkv + 2048, bv, 4096, hipMemcpyDeviceToDevice, stream);
  (void)hipMemsetAsync(ctr, 0, 4, stream);

  gemm_bt<1><<<dim3(24, 64), 256, 0, stream>>>(xb, wqkv, bqkv, fc, qkv, BTX, 3072, 1024);
  transpose_v<<<dim3(32, 64), 256, 0, stream>>>(qkv + 2 * (size_t)8388608, vT);
  flash_fwd<<<dim3(768), 256, 0, stream>>>(qkv, qkv + (size_t)8388608, vT, yb, ctr);
  gemm_bt<0><<<dim3(8, 64), 256, 0, stream>>>(yb, wp, bp, nullptr, (float*)d_out, BTX, 1024, 1024);
}

// Round 9
// 246.618 us; speedup vs baseline: 1.6411x; 1.1504x over previous
//
#include <hip/hip_runtime.h>
#include <hip/hip_bf16.h>

#define TB 2048
#define CC 1024
#define NH 16
#define HD 64
#define NB 4
#define BHX (NB*NH)    // 64
#define BTX (NB*TB)    // 8192
#define NITEMS 2048

typedef __attribute__((ext_vector_type(8))) short bf16x8;
typedef __attribute__((ext_vector_type(4))) float f32x4;
typedef __attribute__((ext_vector_type(4))) unsigned short us4;

__device__ __forceinline__ unsigned short bfb(float f) {
  __hip_bfloat16 h = __float2bfloat16(f);
  return __builtin_bit_cast(unsigned short, h);
}
__device__ __forceinline__ float fexp2(float x) {
  return __builtin_amdgcn_exp2f(x);   // v_exp_f32 (2^x)
}
template <int CTRL>
__device__ __forceinline__ float dppf(float x) {
  int r = __builtin_amdgcn_update_dpp(0, __builtin_bit_cast(int, x), CTRL, 0xf, 0xf, false);
  return __builtin_bit_cast(float, r);
}

__device__ __forceinline__ void gld_lds16(const void* g, void* l) {
  __builtin_amdgcn_global_load_lds(
      (const __attribute__((address_space(1))) unsigned*)g,
      (__attribute__((address_space(3))) unsigned*)l, 16, 0, 0);
}

__global__ void cvt_f32_bf16(const float* __restrict__ src,
                             unsigned short* __restrict__ dst, int n4) {
  int i = blockIdx.x * blockDim.x + threadIdx.x;
  if (i >= n4) return;
  f32x4 v = ((const f32x4*)src)[i];
  us4 o;
#pragma unroll
  for (int j = 0; j < 4; j++) o[j] = bfb(v[j]);
  ((us4*)dst)[i] = o;
}

// 4 weight matrices (1024x1024 f32 each) -> bf16, one launch.
__global__ void cvt_w4(const float* __restrict__ s0, const float* __restrict__ s1,
                       const float* __restrict__ s2, const float* __restrict__ s3,
                       unsigned short* __restrict__ d0, unsigned short* __restrict__ d1,
                       unsigned short* __restrict__ d2, unsigned short* __restrict__ d3) {
  int y = blockIdx.y;
  const float* s = y == 0 ? s0 : y == 1 ? s1 : y == 2 ? s2 : s3;
  unsigned short* d = y == 0 ? d0 : y == 1 ? d1 : y == 2 ? d2 : d3;
  int i = blockIdx.x * 256 + threadIdx.x;
  f32x4 v = ((const f32x4*)s)[i];
  us4 o;
#pragma unroll
  for (int j = 0; j < 4; j++) o[j] = bfb(v[j]);
  ((us4*)d)[i] = o;
}

__global__ void prep_bias(const float* __restrict__ bq, const float* __restrict__ bk,
                          const float* __restrict__ bv, float* __restrict__ out) {
  int i = blockIdx.x * 256 + threadIdx.x;   // grid 12*256 = 3072
  float v = i < 1024 ? bq[i] : i < 2048 ? bk[i - 1024] : bv[i - 2048];
  out[i] = v;
}

// C[i][n] = sum_k A[i][k]*Bw[n][k] + bias[n].
// MODE 0: f32 output row-major [M][N] (final projection).
// MODE 1: bf16 output scattered to qkv[part][bh][t][d] layout, with RoPE
//         applied to parts 0,1 (q,k) via shfl partner exchange.
template <int MODE>
__global__ __launch_bounds__(256) void gemm_bt(
    const unsigned short* __restrict__ A, const unsigned short* __restrict__ Bw,
    const float* __restrict__ bias, const float* __restrict__ fcg,
    void* __restrict__ Cout, int M, int N, int K)
{
  __shared__ __align__(16) unsigned short As[128 * 32];
  __shared__ __align__(16) unsigned short Bs[128 * 32];
  int tid = threadIdx.x;
  int lane = tid & 63, wid = tid >> 6;
  int g = lane >> 4, l4 = lane & 15;
  int wr = wid >> 1, wc = wid & 1;
  int brow = blockIdx.y * 128, bcol = blockIdx.x * 128;

  const unsigned short* ap = A + (size_t)(brow + (tid >> 2)) * K + (tid & 3) * 8;
  const unsigned short* bp_ = Bw + (size_t)(bcol + (tid >> 2)) * K + (tid & 3) * 8;
  const size_t rstep = (size_t)64 * K;
  unsigned short* asl = As + tid * 8;
  unsigned short* bsl = Bs + tid * 8;

  f32x4 acc[4][4] = {};

  for (int k0 = 0; k0 < K; k0 += 32) {
    gld_lds16(ap, asl);
    gld_lds16(ap + rstep, asl + 2048);
    gld_lds16(bp_, bsl);
    gld_lds16(bp_ + rstep, bsl + 2048);
    ap += 32; bp_ += 32;
    __syncthreads();
    bf16x8 af[4], bfr[4];
#pragma unroll
    for (int i = 0; i < 4; i++)
      af[i] = *(const bf16x8*)&As[(wr * 64 + i * 16 + l4) * 32 + g * 8];
#pragma unroll
    for (int i = 0; i < 4; i++)
      bfr[i] = *(const bf16x8*)&Bs[(wc * 64 + i * 16 + l4) * 32 + g * 8];
#pragma unroll
    for (int i = 0; i < 4; i++)
#pragma unroll
      for (int j = 0; j < 4; j++)
        acc[i][j] = __builtin_amdgcn_mfma_f32_16x16x32_bf16(af[i], bfr[j], acc[i][j], 0, 0, 0);
    __syncthreads();
  }

#pragma unroll
  for (int i = 0; i < 4; i++) {
    int grow0 = brow + wr * 64 + i * 16 + 4 * g;
#pragma unroll
    for (int j = 0; j < 4; j++) {
      int gcol = bcol + wc * 64 + j * 16 + l4;
      float bv = bias[gcol];
      if (MODE == 0) {
        float* out = (float*)Cout;
#pragma unroll
        for (int r = 0; r < 4; r++)
          out[(size_t)(grow0 + r) * N + gcol] = acc[i][j][r] + bv;
      } else {
        unsigned short* out = (unsigned short*)Cout;
        int part = gcol >> 10;
        int c = gcol & 1023;
        int h = c >> 6, d = c & 63;
        int dbase = d & ~1;
        float sgn = (d & 1) ? 1.f : -1.f;
        bool isqk = (part < 2);   // uniform across the l4/l4^1 pair
#pragma unroll
        for (int r = 0; r < 4; r++) {
          int grow = grow0 + r;
          int b = grow >> 11, t = grow & 2047;
          float v = acc[i][j][r] + bv;
          float w = __shfl_xor(v, 1, 64);  // partner dim's value
          float o = v;
          if (isqk) {
            float cth = fcg[(size_t)t * 64 + dbase];
            float sth = fcg[(size_t)t * 64 + dbase + 1];
            o = v * cth + sgn * w * sth;
          }
          size_t dst = (size_t)part * ((size_t)BHX * TB * HD)
                     + ((size_t)(b * NH + h) * TB + t) * HD + d;
          out[dst] = bfb(o);
        }
      }
    }
  }
}

// v [bh][T][64] -> vT [bh][64][T], 64x64 tiles. 256 threads, 2 chunks each way.
__global__ void transpose_v(const unsigned short* __restrict__ v,
                            unsigned short* __restrict__ vT) {
  int bh = blockIdx.y, t0 = blockIdx.x * 64;
  __shared__ __align__(16) unsigned short tile[64][72];
  int tid = threadIdx.x;
#pragma unroll
  for (int s = 0; s < 2; s++) {
    int cid = tid + 256 * s;
    int r = cid >> 3, c8 = (cid & 7) * 8;
    bf16x8 val = *(const bf16x8*)(v + ((size_t)bh * TB + t0 + r) * HD + c8);
    *(bf16x8*)&tile[r][c8] = val;
  }
  __syncthreads();
#pragma unroll
  for (int s = 0; s < 2; s++) {
    int cid = tid + 256 * s;
    int rr = cid >> 3, cc = (cid & 7) * 8;
    bf16x8 o;
#pragma unroll
    for (int i = 0; i < 8; i++) o[i] = (short)tile[cc + i][rr];
    *(bf16x8*)(vT + ((size_t)bh * HD + rr) * TB + t0 + cc) = o;
  }
}

// Flash attention fwd, causal. Work-stealing over 2048 items (bh, q64):
// 64 q-rows per item, 4 waves x 16 rows, KV tiles of 64. Heavy items first.
// K pre-roped, V^T pre-transposed; double-buffered global_load_lds staging
// with XOR-swizzled source. Softmax reductions via DPP row_ror (VALU, not
// LDS-pipe). Ps swizzled & unpadded; s_item aliased into Ps so LDS = 40960 B
// exactly -> 4 blocks/CU.
__global__ __launch_bounds__(256, 4) void flash_fwd(
    const unsigned short* __restrict__ q, const unsigned short* __restrict__ k,
    const unsigned short* __restrict__ vT, unsigned short* __restrict__ yb,
    int* __restrict__ ctr)
{
  __shared__ __align__(16) unsigned short Ks[2][4096];  // linear, swz content
  __shared__ __align__(16) unsigned short Vs[2][4096];
  __shared__ __align__(16) unsigned short Ps[4][16][64]; // swizzled; [0][0][0..1] = item bcast

  const int tid = threadIdx.x, wid = tid >> 6, lane = tid & 63;
  const int g = lane >> 4, l4 = lane & 15;

  // fixed staging geometry: 2 passes x 16B per thread per tile
  const int off0 = tid << 4;
  const int row0 = off0 >> 7, sc0 = ((off0 >> 4) & 7) ^ (row0 & 7);
  const int off1 = off0 + 4096;
  const int row1 = off1 >> 7, sc1 = ((off1 >> 4) & 7) ^ (row1 & 7);
  const int koff0 = (row0 << 6) + (sc0 << 3);
  const int koff1 = (row1 << 6) + (sc1 << 3);
  const int voff0 = (row0 << 11) + (sc0 << 3);
  const int voff1 = (row1 << 11) + (sc1 << 3);

  const float SCL2 = 0.18033688011112042f;  // 1/8 * log2(e)

  for (;;) {
    __syncthreads();   // all waves done with Ps before s_item overwrite
    if (tid == 0) *(int*)&Ps[0][0][0] = atomicAdd(ctr, 1);
    __syncthreads();
    const int w = *(const int*)&Ps[0][0][0];
    if (w >= NITEMS) break;
    const int q64 = 31 - (w >> 6), bh = w & 63;
    const int rbase = q64 * 64 + wid * 16;   // wave's absolute q-row base

    const unsigned short* kb = k  + ((size_t)bh << 17);  // bh*T*HD
    const unsigned short* vb = vT + ((size_t)bh << 17);  // bh*HD*T

    // Q fragments (pre-roped by GEMM epilogue)
    bf16x8 qf0, qf1;
    {
      const unsigned short* qp = q + (((size_t)bh * TB + rbase + l4) << 6);
      qf0 = *(const bf16x8*)(qp + g * 8);
      qf1 = *(const bf16x8*)(qp + 32 + g * 8);
    }

    float m_run[4], l_run[4];
    f32x4 acc_o[4] = {};
#pragma unroll
    for (int j = 0; j < 4; j++) { m_run[j] = -1e30f; l_run[j] = 0.f; }

    // Prologue: stage tile 0 into buf 0.
    gld_lds16(kb + koff0, &Ks[0][off0 >> 1]);
    gld_lds16(kb + koff1, &Ks[0][off1 >> 1]);
    gld_lds16(vb + voff0, &Vs[0][off0 >> 1]);
    gld_lds16(vb + voff1, &Vs[0][off1 >> 1]);
    __syncthreads();   // auto vmcnt(0): tile 0 ready

    for (int kt = 0; kt <= q64; kt++) {
      const int cur = kt & 1;
      if (kt < q64) {   // issue next tile's loads; they fly during compute
        const int kadd = (kt + 1) << 12;
        const int vadd = (kt + 1) << 6;
        gld_lds16(kb + koff0 + kadd, &Ks[cur ^ 1][off0 >> 1]);
        gld_lds16(kb + koff1 + kadd, &Ks[cur ^ 1][off1 >> 1]);
        gld_lds16(vb + voff0 + vadd, &Vs[cur ^ 1][off0 >> 1]);
        gld_lds16(vb + voff1 + vadd, &Vs[cur ^ 1][off1 >> 1]);
      }
      const unsigned short* Kc = Ks[cur];
      const unsigned short* Vc = Vs[cur];

      // S = Q K^T (16 q-rows x 64 kv), exp2-domain scale + causal mask.
      float sv[4][4];
      __builtin_amdgcn_s_setprio(1);
#pragma unroll
      for (int cb = 0; cb < 4; cb++) {
        const int r = cb * 16 + l4;
        const int sw = (r & 7) * 8;
        bf16x8 kb0 = *(const bf16x8*)&Kc[r * 64 + ((g * 8) ^ sw)];
        bf16x8 kb1 = *(const bf16x8*)&Kc[r * 64 + (((g + 4) * 8) ^ sw)];
        f32x4 z = {0.f, 0.f, 0.f, 0.f};
        z = __builtin_amdgcn_mfma_f32_16x16x32_bf16(qf0, kb0, z, 0, 0, 0);
        z = __builtin_amdgcn_mfma_f32_16x16x32_bf16(qf1, kb1, z, 0, 0, 0);
#pragma unroll
        for (int j = 0; j < 4; j++)
          sv[cb][j] = z[j] * SCL2;
      }
      __builtin_amdgcn_s_setprio(0);
      if (kt == q64) {             // wave-uniform diagonal tile: causal mask
        const int rq = wid * 16 + 4 * g;
#pragma unroll
        for (int cb = 0; cb < 4; cb++)
#pragma unroll
          for (int j = 0; j < 4; j++)
            if (cb * 16 + l4 > rq + j) sv[cb][j] = -1e30f;
      }

      // Row max via DPP rotate-reduce (rows live in 16-lane DPP rows).
      float mt[4];
#pragma unroll
      for (int j = 0; j < 4; j++) {
        float m = fmaxf(fmaxf(sv[0][j], sv[1][j]), fmaxf(sv[2][j], sv[3][j]));
        m = fmaxf(m, dppf<0x121>(m));
        m = fmaxf(m, dppf<0x122>(m));
        m = fmaxf(m, dppf<0x124>(m));
        m = fmaxf(m, dppf<0x128>(m));
        mt[j] = m;
      }
      // Defer-max: rescale only when max grew by > 8 (log2 domain).
      bool need = !((mt[0] <= m_run[0] + 8.f) & (mt[1] <= m_run[1] + 8.f) &
                    (mt[2] <= m_run[2] + 8.f) & (mt[3] <= m_run[3] + 8.f));
      if (__any(need)) {
#pragma unroll
        for (int j = 0; j < 4; j++) {
          float mn = fmaxf(m_run[j], mt[j]);
          float alpha = fexp2(m_run[j] - mn);
          m_run[j] = mn;
          l_run[j] *= alpha;
#pragma unroll
          for (int db = 0; db < 4; db++) acc_o[db][j] *= alpha;
        }
      }
      // exp + row-sum via DPP rotate-reduce.
#pragma unroll
      for (int j = 0; j < 4; j++) {
        float s0 = fexp2(sv[0][j] - m_run[j]); sv[0][j] = s0;
        float s1 = fexp2(sv[1][j] - m_run[j]); sv[1][j] = s1;
        float s2 = fexp2(sv[2][j] - m_run[j]); sv[2][j] = s2;
        float s3 = fexp2(sv[3][j] - m_run[j]); sv[3][j] = s3;
        float p = (s0 + s1) + (s2 + s3);
        p += dppf<0x121>(p);
        p += dppf<0x122>(p);
        p += dppf<0x124>(p);
        p += dppf<0x128>(p);
        l_run[j] += p;
      }

      // P -> LDS (per-wave region, XOR-swizzled) -> A-fragment for PV.
#pragma unroll
      for (int cb = 0; cb < 4; cb++)
#pragma unroll
        for (int j = 0; j < 4; j++) {
          const int xch = (cb * 2 + (l4 >> 3)) ^ ((g & 1) * 4 + j);
          Ps[wid][4 * g + j][xch * 8 + (l4 & 7)] = bfb(sv[cb][j]);
        }
      asm volatile("s_waitcnt lgkmcnt(0)" ::: "memory");
      __builtin_amdgcn_sched_barrier(0);
      bf16x8 pa0 = *(const bf16x8*)&Ps[wid][l4][(g ^ (l4 & 7)) * 8];
      bf16x8 pa1 = *(const bf16x8*)&Ps[wid][l4][((4 + g) ^ (l4 & 7)) * 8];
      __builtin_amdgcn_s_setprio(1);
#pragma unroll
      for (int db = 0; db < 4; db++) {
        const int r = db * 16 + l4;
        const int sw = (r & 7) * 8;
        bf16x8 vb0 = *(const bf16x8*)&Vc[r * 64 + ((g * 8) ^ sw)];
        bf16x8 vb1 = *(const bf16x8*)&Vc[r * 64 + (((g + 4) * 8) ^ sw)];
        acc_o[db] = __builtin_amdgcn_mfma_f32_16x16x32_bf16(pa0, vb0, acc_o[db], 0, 0, 0);
        acc_o[db] = __builtin_amdgcn_mfma_f32_16x16x32_bf16(pa1, vb1, acc_o[db], 0, 0, 0);
      }
      __builtin_amdgcn_s_setprio(0);
      // Single barrier per tile: auto vmcnt(0) waits next tile's DMA (already
      // flown during compute); auto lgkmcnt(0) covers all waves' LDS reads.
      __syncthreads();
    }

    // Epilogue: normalize and write y[b][t][h*64+d] as bf16.
    unsigned short* yp = yb + ((size_t)(bh >> 4) * TB) * CC + (size_t)(bh & 15) * HD;
    const int qr0 = rbase + 4 * g;
    float inv[4];
#pragma unroll
    for (int j = 0; j < 4; j++) inv[j] = 1.0f / l_run[j];
#pragma unroll
    for (int db = 0; db < 4; db++) {
      const int d = db * 16 + l4;
#pragma unroll
      for (int j = 0; j < 4; j++)
        yp[(size_t)(qr0 + j) * CC + d] = bfb(acc_o[db][j] * inv[j]);
    }
  }
}

extern "C" void kernel_launch(void* const* d_in, const int* in_sizes, int n_in,
                              void* d_out, int out_size, void* d_ws, size_t ws_size,
                              hipStream_t stream) {
  (void)in_sizes; (void)n_in; (void)out_size; (void)ws_size;
  const float* x  = (const float*)d_in[0];
  const float* fc = (const float*)d_in[1];
  // d_in[2]=attn_mask (tril), d_in[3]=padding_mask (all ones): applied analytically.
  const float* Wq = (const float*)d_in[4];
  const float* bq = (const float*)d_in[5];
  const float* Wk = (const float*)d_in[6];
  const float* bk = (const float*)d_in[7];
  const float* Wv = (const float*)d_in[8];
  const float* bv = (const float*)d_in[9];
  const float* Wp = (const float*)d_in[10];
  const float* bp = (const float*)d_in[11];

  char* ws = (char*)d_ws;
  unsigned short* xb   = (unsigned short*)(ws + 0);          // 8192x1024 bf16 (later reused as yb)
  unsigned short* wqkv = (unsigned short*)(ws + 16777216);   // 3072x1024 bf16
  unsigned short* wp   = (unsigned short*)(ws + 23068672);   // 1024x1024 bf16
  float*          bqkv = (float*)(ws + 25165824);            // 3072 f32
  int*            ctr  = (int*)(ws + 25178112);              // work-steal counter
  unsigned short* qkv  = (unsigned short*)(ws + 25182208);   // 3 x [64][2048][64] bf16
  unsigned short* vT   = qkv + 3 * (size_t)8388608;          // [64][64][2048] bf16
  unsigned short* yb   = xb;

  cvt_f32_bf16<<<(2097152 + 255) / 256, 256, 0, stream>>>(x, xb, 2097152);
  cvt_w4<<<dim3(1024, 4), 256, 0, stream>>>(Wq, Wk, Wv, Wp,
      wqkv, wqkv + 1048576, wqkv + 2097152, wp);
  prep_bias<<<dim3(12), 256, 0, stream>>>(bq, bk, bv, bqkv);
  (void)hipMemsetAsync(ctr, 0, 4, stream);

  gemm_bt<1><<<dim3(24, 64), 256, 0, stream>>>(xb, wqkv, bqkv, fc, qkv, BTX, 3072, 1024);
  transpose_v<<<dim3(32, 64), 256, 0, stream>>>(qkv + 2 * (size_t)8388608, vT);
  flash_fwd<<<dim3(1024), 256, 0, stream>>>(qkv, qkv + (size_t)8388608, vT, yb, ctr);
  gemm_bt<0><<<dim3(8, 64), 256, 0, stream>>>(yb, wp, bp, nullptr, (float*)d_out, BTX, 1024, 1024);
}